// Round 13
// baseline (565.235 us; speedup 1.0000x reference)
//
#include <hip/hip_runtime.h>
#include <hip/hip_bf16.h>
#include <math.h>
#include <stdint.h>

typedef __hip_bfloat16 bf16;
using f32x4 = __attribute__((ext_vector_type(4))) float;
using s16x8 = __attribute__((ext_vector_type(8))) short;

constexpr int Bc = 2, Sc = 2048, Hc = 2048, NHc = 32, HDc = 64;
constexpr int Mc = Bc * Sc;      // 4096 rows
constexpr int MAXPOS = 8192;

// ---------------- workspace layout (bytes) ----------------
constexpr size_t OFF_WV  = 0;
constexpr size_t OFF_WQK = OFF_WV  + (size_t)Hc * Hc * 2;
constexpr size_t OFF_WO  = OFF_WQK + (size_t)2 * Hc * Hc * 2;
constexpr size_t OFF_W1  = OFF_WO  + (size_t)Hc * Hc * 2;
constexpr size_t OFF_W2  = OFF_W1  + (size_t)(Hc/2) * (2*Hc) * 2;
constexpr size_t OFF_HS  = OFF_W2  + (size_t)Hc * Hc * 2;
constexpr size_t OFF_XPR = OFF_HS  + (size_t)Mc * Hc * 2;
constexpr size_t OFF_O1  = OFF_XPR + (size_t)Mc * Hc * 2;
constexpr size_t OFF_O1P = OFF_O1  + (size_t)Mc * (Hc/2) * 2;
constexpr size_t OFF_O2  = OFF_O1P + (size_t)Mc * (Hc/2) * 2;
constexpr size_t OFF_LF  = OFF_O2  + (size_t)Mc * Hc * 4;
constexpr size_t OFF_VT  = OFF_LF  + (size_t)Mc * Hc * 2;
constexpr size_t OFF_COS = OFF_VT  + (size_t)Mc * Hc * 2;
constexpr size_t OFF_SIN = OFF_COS + (size_t)MAXPOS * HDc * 4;
constexpr size_t OFF_Q   = OFF_XPR;  // q over xprev
constexpr size_t OFF_K   = OFF_HS;   // k over hs
constexpr size_t OFF_CTX = OFF_O1;   // ctx over o1+o1prev

// ---------------- helpers ----------------
__device__ __forceinline__ f32x4 mfma16(s16x8 a, s16x8 b, f32x4 c) {
  return __builtin_amdgcn_mfma_f32_16x16x32_bf16(a, b, c, 0, 0, 0);
}
__device__ __forceinline__ void gload16(const bf16* g, bf16* l) {
  __builtin_amdgcn_global_load_lds(
      (__attribute__((address_space(1))) void*)g,
      (__attribute__((address_space(3))) void*)l, 16, 0, 0);
}
__device__ __forceinline__ uint16_t bfbits(float x) {
  union { bf16 h; uint16_t u; } v; v.h = __float2bfloat16(x); return v.u;
}
__device__ __forceinline__ uint32_t pkbf(float a, float b) {
  return (uint32_t)bfbits(a) | ((uint32_t)bfbits(b) << 16);
}
__device__ __forceinline__ void block_bar() {
  asm volatile("" ::: "memory");
  __builtin_amdgcn_s_barrier();
  asm volatile("" ::: "memory");
}
template <int N> __device__ __forceinline__ void vm_wait() {
  if constexpr (N == 0)      asm volatile("s_waitcnt vmcnt(0)" ::: "memory");
  else if constexpr (N == 2) asm volatile("s_waitcnt vmcnt(2)" ::: "memory");
  else if constexpr (N == 3) asm volatile("s_waitcnt vmcnt(3)" ::: "memory");
  else if constexpr (N == 4) asm volatile("s_waitcnt vmcnt(4)" ::: "memory");
  else if constexpr (N == 6) asm volatile("s_waitcnt vmcnt(6)" ::: "memory");
  else if constexpr (N == 8) asm volatile("s_waitcnt vmcnt(8)" ::: "memory");
}

// ---------------- small conversion kernels ----------------
__global__ void k_cvt(const float* __restrict__ in, bf16* __restrict__ out, int n) {
  int i = blockIdx.x * 256 + threadIdx.x;
  if (i < n) out[i] = __float2bfloat16(in[i]);
}

__global__ void k_cvt_hs(const float* __restrict__ hs, const float* __restrict__ lf1,
                         bf16* __restrict__ hsb, bf16* __restrict__ xprev) {
  int i = blockIdx.x * 256 + threadIdx.x;      // over M*H
  if (i >= Mc * Hc) return;
  float v = hs[i];
  bf16 b = __float2bfloat16(v);
  hsb[i] = b;
  int row = i >> 11, col = i & (Hc - 1);
  int s = row & (Sc - 1), bb = row >> 11;
  if (s + 1 < Sc) xprev[i + Hc] = b;
  if (s == 0)     xprev[i] = __float2bfloat16(lf1[bb * Hc + col]);
}

__global__ void k_repack1(const float* __restrict__ w, bf16* __restrict__ out) {
  int i = blockIdx.x * 256 + threadIdx.x;      // 1024*4096
  if (i >= (Hc/2) * 2 * Hc) return;
  int oc = i >> 12, k = i & 4095;
  int ic = k & (Hc - 1), t = k >> 11;
  out[i] = __float2bfloat16(w[((size_t)oc * Hc + ic) * 2 + t]);
}
__global__ void k_repack2(const float* __restrict__ w, bf16* __restrict__ out) {
  int i = blockIdx.x * 256 + threadIdx.x;      // 2048*2048
  if (i >= Hc * Hc) return;
  int c = i >> 11, k = i & (Hc - 1);
  int oc = k & (Hc/2 - 1), t = k >> 10;
  out[i] = __float2bfloat16(w[((size_t)c * (Hc/2) + oc) * 2 + t]);
}

__global__ void k_prefill_o1p(const float* __restrict__ lf2, bf16* __restrict__ o1p) {
  int i = blockIdx.x * 256 + threadIdx.x;      // B * H/2
  if (i >= Bc * (Hc/2)) return;
  int b = i >> 10, n = i & (Hc/2 - 1);
  o1p[(size_t)b * Sc * (Hc/2) + n] = __float2bfloat16(lf2[i]);
}

struct InvF { double v[32]; double mscale; };

__global__ void k_costab(InvF f, float* __restrict__ ct, float* __restrict__ st) {
  int i = blockIdx.x * 256 + threadIdx.x;      // MAXPOS*64
  if (i >= MAXPOS * HDc) return;
  int p = i >> 6, d = i & 63;
  double ang = (double)p * f.v[d & 31];
  ct[i] = (float)(cos(ang) * f.mscale);
  st[i] = (float)(sin(ang) * f.mscale);
}

// ---------------- RMSNorm (block per row) ----------------
__global__ __launch_bounds__(256) void k_rmsnorm(const float* __restrict__ x,
                                                 const float* __restrict__ w,
                                                 bf16* __restrict__ out) {
  __shared__ float red[4];
  int row = blockIdx.x;
  const float* xr = x + (size_t)row * Hc;
  float ss = 0.f;
  for (int c = threadIdx.x; c < Hc; c += 256) { float v = xr[c]; ss += v * v; }
  for (int off = 32; off; off >>= 1) ss += __shfl_down(ss, off, 64);
  if ((threadIdx.x & 63) == 0) red[threadIdx.x >> 6] = ss;
  __syncthreads();
  float sc = rsqrtf((red[0] + red[1] + red[2] + red[3]) / Hc + 1e-6f);
  for (int c = threadIdx.x; c < Hc; c += 256)
    out[(size_t)row * Hc + c] = __float2bfloat16(xr[c] * sc * w[c]);
}

// ---------------- triple-buffered counted-vmcnt GEMM (512 thr, 8 waves) ---
// C[M,N] = A[M,K] @ W[N,K]^T. 3 LDS slots; stage tile t+2 while computing t;
// raw s_barrier + counted vmcnt (never 0 in main loop). Paired-row LDS pack
// with XOR chunk swizzle (rule #21). Rect XCD swizzle.
// Tile configs: 256x256 (waves 2Mx4N, 128x64/wave), 256x128 (4Mx2N, 64x64),
// 128x128 (2Mx4N, 64x32).
// EPI: 1 conv1 (+bias, dual store via out2) | 2 +bias+resid fp32 | 4 fp32
//      | 5 v^T store | 6 fused-RoPE q/k writer (BN=256 only)
template <int EPI, int BM, int BN>
__global__ __launch_bounds__(512, 2) void gemm8(
    const bf16* __restrict__ A0, const bf16* __restrict__ A1, int Ksplit,
    const bf16* __restrict__ Bw, int K, int N, void* __restrict__ Cout,
    const float* __restrict__ bias, const float* __restrict__ resid,
    const int* __restrict__ pos, const float* __restrict__ ct,
    const float* __restrict__ st, bf16* __restrict__ out2) {
  constexpr int L = (BM + BN) / 128;            // gload16 per thread per tile
  constexpr int TILE = (BM + BN) * 32;
  constexpr int MF = (BM == 256) ? ((BN == 256) ? 8 : 4) : 4;
  constexpr int NF = (BN == 256) ? 4 : ((BM == 256) ? 4 : 2);
  __shared__ __align__(16) bf16 lds[3][TILE];
  const int tid = threadIdx.x;
  const int w = tid >> 6, l = tid & 63;
  const int lrow = l & 15, lg = l >> 4;
  const int wm = (BM == 256) ? ((BN == 256) ? (w >> 2) * 128 : (w & 3) * 64)
                             : (w >> 2) * 64;
  const int wn = (BM == 256) ? ((BN == 256) ? (w & 3) * 64 : (w >> 2) * 64)
                             : (w & 3) * 32;
  // rect XCD swizzle: XCD c gets a (gx/4)x(gy/2) block rectangle
  const int gx = gridDim.x;
  const int lin = blockIdx.y * gx + blockIdx.x;
  const int cx = gx >> 2, cy = gridDim.y >> 1;
  const int c = lin & 7, idx = lin >> 3;
  const int bn = (c & 3) * cx + idx % cx;
  const int bm = (c >> 2) * cy + idx / cx;

  auto ld1 = [&](const bf16* srcbase, size_t stride, bf16* ldst, int ci) {
    const int pr = ci >> 3, rem = ci & 7;
    const int r = pr * 2 + (rem >> 2), g = (rem & 3) ^ (pr & 3);
    gload16(srcbase + (size_t)r * stride + g * 8, ldst + ci * 8);
  };
  auto stage = [&](int kt, int slot) {
    const int kcol = kt * 32;
    const bf16* Au; int kc;
    if (kcol < Ksplit) { Au = A0; kc = kcol; } else { Au = A1; kc = kcol - Ksplit; }
    const bf16* As_ = Au + (size_t)bm * BM * Ksplit + kc;
    bf16* ldsA = lds[slot];
    ld1(As_, Ksplit, ldsA, tid);
    if constexpr (BM == 256) ld1(As_, Ksplit, ldsA, tid + 512);
    const bf16* Bs_ = Bw + (size_t)bn * BN * K + kcol;
    bf16* ldsB = lds[slot] + BM * 32;
    ld1(Bs_, K, ldsB, tid);
    if constexpr (BN == 256) ld1(Bs_, K, ldsB, tid + 512);
  };
  auto frag = [&](const bf16* base, int r) -> s16x8 {
    const int s = ((r >> 1) << 3) + ((r & 1) << 2) + (lg ^ ((r >> 1) & 3));
    return *(const s16x8*)(base + s * 8);
  };

  f32x4 acc[MF][NF] = {};
  const int nkt = K / 32;
  stage(0, 0);
  stage(1, 1);
  for (int t = 0; t < nkt; ++t) {
    if (t + 2 < nkt) { stage(t + 2, (t + 2) % 3); vm_wait<2 * L>(); }
    else if (t + 1 < nkt) { vm_wait<L>(); }
    else { vm_wait<0>(); }
    block_bar();
    const bf16* Asl = lds[t % 3];
    const bf16* Bsl = Asl + BM * 32;
    s16x8 af[MF], bfr[NF];
#pragma unroll
    for (int m = 0; m < MF; ++m) af[m] = frag(Asl, wm + m * 16 + lrow);
#pragma unroll
    for (int n = 0; n < NF; ++n) bfr[n] = frag(Bsl, wn + n * 16 + lrow);
    __builtin_amdgcn_s_setprio(1);
#pragma unroll
    for (int m = 0; m < MF; ++m)
#pragma unroll
      for (int n = 0; n < NF; ++n)
        acc[m][n] = mfma16(af[m], bfr[n], acc[m][n]);
    __builtin_amdgcn_s_setprio(0);
    block_bar();
  }
  if constexpr (EPI == 6) {
    // fused RoPE: wave's 64-col window = one (head, q|k) half. Pairs are
    // acc[m][n] (d) / acc[m][n+2] (d+32), n in {0,1}.
    const int gcol0 = bn * BN + wn;            // wave-uniform
    const int h = gcol0 >> 7, half = (gcol0 >> 6) & 1;
    bf16* outp = half ? out2 : (bf16*)Cout;
    const float qsc = half ? 1.0f : 0.125f * 1.44269504088896f;
#pragma unroll
    for (int m = 0; m < MF; ++m)
#pragma unroll
      for (int r = 0; r < 4; ++r) {
        const int grow = bm * BM + wm + m * 16 + lg * 4 + r;
        const int p = pos[grow];
        const int bb = grow >> 11, s = grow & (Sc - 1);
        bf16* rowp = outp + ((size_t)(bb * NHc + h) * Sc + s) * 64;
#pragma unroll
        for (int n = 0; n < 2; ++n) {
          const int dd = n * 16 + lrow;
          const float c0 = ct[p * 64 + dd],      s0 = st[p * 64 + dd];
          const float c1 = ct[p * 64 + 32 + dd], s1 = st[p * 64 + 32 + dd];
          const float v0 = acc[m][n][r], v1 = acc[m][n + 2][r];
          rowp[dd]      = __float2bfloat16((v0 * c0 - v1 * s0) * qsc);
          rowp[dd + 32] = __float2bfloat16((v1 * c1 + v0 * s1) * qsc);
        }
      }
  } else {
#pragma unroll
    for (int m = 0; m < MF; ++m)
#pragma unroll
      for (int n = 0; n < NF; ++n)
#pragma unroll
        for (int r = 0; r < 4; ++r) {
          const int grow = bm * BM + wm + m * 16 + lg * 4 + r;
          const int gcol = bn * BN + wn + n * 16 + lrow;
          float v = acc[m][n][r];
          if constexpr (EPI == 1) {
            v += bias[gcol];
            bf16 bv = __float2bfloat16(v);
            ((bf16*)Cout)[(size_t)grow * N + gcol] = bv;
            if ((grow & (Sc - 1)) != Sc - 1) out2[(size_t)(grow + 1) * N + gcol] = bv;
          } else if constexpr (EPI == 2) {
            v += bias[gcol] + resid[(size_t)grow * N + gcol];
            ((float*)Cout)[(size_t)grow * N + gcol] = v;
          } else if constexpr (EPI == 5) {
            const int b = gcol >> 11, s = gcol & (Sc - 1);
            ((bf16*)Cout)[((size_t)(b * Hc + grow)) * Sc + s] = __float2bfloat16(v);
          } else {
            ((float*)Cout)[(size_t)grow * N + gcol] = v;
          }
        }
  }
}

// ---------------- causal flash attention (merged mirror passes) -----------
// 8 waves / 512 threads: waves 0-3 own rows [128t, 128t+128), waves 4-7 the
// mirrored rows [1920-128t, 2048-128t). One kv-loop of NT = 32-2t tiles with
// SHARED K/V staging (the low set's staging was fully redundant before).
// 2-slot double buffer + __syncthreads (the occupancy-safe protocol).
// LDS 72KB -> 2 blocks/CU = 16 waves/CU = 4 waves/SIMD (vs 3 before).
__global__ __launch_bounds__(512, 4) void k_attn(const bf16* __restrict__ Q,
                                                 const bf16* __restrict__ Kg,
                                                 const bf16* __restrict__ Vt,
                                                 bf16* __restrict__ ctx) {
  __shared__ __align__(16) bf16 Ks[2][64 * 64];
  __shared__ __align__(16) bf16 Vs[2][64 * 64];
  __shared__ __align__(16) uint32_t Pl[8][2][2][16][20];
  const int tid = threadIdx.x;
  const int w = tid >> 6, l = tid & 63;
  const int lrow = l & 15, lg = l >> 4, lk = lg * 8;
  const int bh = blockIdx.x;
  const int tile = blockIdx.y;         // 0..7
  const bf16* Qp = Q  + (size_t)bh * Sc * HDc;
  const bf16* Kp = Kg + (size_t)bh * Sc * HDc;
  const bf16* Vp = Vt + (size_t)bh * HDc * Sc;
  const int b = bh >> 5, h = bh & 31;
  const s16x8 ones8 = {16256, 16256, 16256, 16256, 16256, 16256, 16256, 16256};

  const int set = w >> 2, ws = w & 3;
  const int base = (set == 0) ? tile * 128 : (Sc - 128 - tile * 128);
  const int q0 = base + ws * 32;
  const int NT = 32 - 2 * tile;        // covers the high (mirror) set

  const int srow0 = tid >> 3, schunk = tid & 7;   // 512 thr: rows 0..63

  auto stage = [&](int kv0, int buf) {
    gload16(Kp + (size_t)(kv0 + srow0) * 64 + ((schunk ^ (srow0 & 7)) << 3),
            &Ks[buf][tid * 8]);
    gload16(Vp + (size_t)srow0 * Sc + kv0 + ((schunk ^ (srow0 & 7)) << 3),
            &Vs[buf][tid * 8]);
  };

  s16x8 qa[2][2];
#pragma unroll
  for (int m = 0; m < 2; ++m)
#pragma unroll
    for (int hf = 0; hf < 2; ++hf)
      qa[m][hf] = *(const s16x8*)&Qp[(size_t)(q0 + m * 16 + lrow) * 64 + hf * 32 + lk];

  f32x4 o[2][4] = {};
  f32x4 lsf[2] = {};
  float mx[2] = {-1e30f, -1e30f};

  stage(0, 0);
  __syncthreads();

  for (int t = 0; t < NT; ++t) {
    const int cur = t & 1;
    const int kv0 = t * 64;
    if (t + 1 < NT) stage(kv0 + 64, cur ^ 1);
    if (kv0 <= q0) {                   // wave-uniform guard
      s16x8 kc[8], vc[4][2];
#pragma unroll
      for (int c = 0; c < 4; ++c)
#pragma unroll
        for (int hf = 0; hf < 2; ++hf) {
          const int row = c * 16 + lrow;
          kc[c * 2 + hf] =
              *(const s16x8*)&Ks[cur][row * 64 + (((hf << 2) + lg) ^ (row & 7)) * 8];
        }
#pragma unroll
      for (int db = 0; db < 4; ++db)
#pragma unroll
        for (int kh = 0; kh < 2; ++kh) {
          const int row = db * 16 + lrow;
          vc[db][kh] =
              *(const s16x8*)&Vs[cur][row * 64 + (((kh << 2) + lg) ^ (row & 7)) * 8];
        }
      const bool lastit = (kv0 + 64 > q0);

#pragma unroll
      for (int m = 0; m < 2; ++m) {
        f32x4 s[4];
        __builtin_amdgcn_s_setprio(1);
#pragma unroll
        for (int c = 0; c < 4; ++c) {
          f32x4 z = {};
          z = mfma16(kc[c * 2], qa[m][0], z);
          z = mfma16(kc[c * 2 + 1], qa[m][1], z);
          s[c] = z;
        }
        __builtin_amdgcn_s_setprio(0);

        if (lastit) {
          const int qq = q0 + m * 16 + lrow;
#pragma unroll
          for (int c = 0; c < 4; ++c)
#pragma unroll
            for (int r = 0; r < 4; ++r)
              if (kv0 + c * 16 + lg * 4 + r > qq) s[c][r] = -1e30f;
        }
        float t16 = fmaxf(
            fmaxf(fmaxf(fmaxf(s[0][0], s[0][1]), fmaxf(s[0][2], s[0][3])),
                  fmaxf(fmaxf(s[1][0], s[1][1]), fmaxf(s[1][2], s[1][3]))),
            fmaxf(fmaxf(fmaxf(s[2][0], s[2][1]), fmaxf(s[2][2], s[2][3])),
                  fmaxf(fmaxf(s[3][0], s[3][1]), fmaxf(s[3][2], s[3][3]))));
        if (!__all(t16 <= mx[m] + 8.0f)) {
          t16 = fmaxf(t16, __shfl_xor(t16, 16, 64));
          t16 = fmaxf(t16, __shfl_xor(t16, 32, 64));
          const float mnew = fmaxf(mx[m], t16);
          const float sold = __builtin_amdgcn_exp2f(mx[m] - mnew);
          mx[m] = mnew;
          lsf[m] *= sold;
#pragma unroll
          for (int db = 0; db < 4; ++db) o[m][db] *= sold;
        }
        float p[4][4];
#pragma unroll
        for (int c = 0; c < 4; ++c)
#pragma unroll
          for (int r = 0; r < 4; ++r)
            p[c][r] = __builtin_amdgcn_exp2f(s[c][r] - mx[m]);
#pragma unroll
        for (int kh = 0; kh < 2; ++kh) {
          *(uint64_t*)&Pl[w][m][kh][lrow][lg * 2] =
              (uint64_t)pkbf(p[kh * 2][0], p[kh * 2][1]) |
              ((uint64_t)pkbf(p[kh * 2][2], p[kh * 2][3]) << 32);
          *(uint64_t*)&Pl[w][m][kh][lrow][8 + lg * 2] =
              (uint64_t)pkbf(p[kh * 2 + 1][0], p[kh * 2 + 1][1]) |
              ((uint64_t)pkbf(p[kh * 2 + 1][2], p[kh * 2 + 1][3]) << 32);
        }
        const s16x8 pb0 = *(const s16x8*)&Pl[w][m][0][lrow][lg * 4];
        const s16x8 pb1 = *(const s16x8*)&Pl[w][m][1][lrow][lg * 4];
        __builtin_amdgcn_s_setprio(1);
#pragma unroll
        for (int db = 0; db < 4; ++db) o[m][db] = mfma16(vc[db][0], pb0, o[m][db]);
        lsf[m] = mfma16(ones8, pb0, lsf[m]);
#pragma unroll
        for (int db = 0; db < 4; ++db) o[m][db] = mfma16(vc[db][1], pb1, o[m][db]);
        lsf[m] = mfma16(ones8, pb1, lsf[m]);
        __builtin_amdgcn_s_setprio(0);
      }
    }
    __syncthreads();                   // drains stage vmcnt; protects buf reuse
  }
#pragma unroll
  for (int m = 0; m < 2; ++m) {
    const float inv = 1.0f / lsf[m][0];
    const int qrow = q0 + m * 16 + lrow;
    const size_t rowoff = ((size_t)(b * Sc + qrow)) * Hc + h * 64;
#pragma unroll
    for (int db = 0; db < 4; ++db) {
      uint64_t pk = (uint64_t)bfbits(o[m][db][0] * inv) |
                    ((uint64_t)bfbits(o[m][db][1] * inv) << 16) |
                    ((uint64_t)bfbits(o[m][db][2] * inv) << 32) |
                    ((uint64_t)bfbits(o[m][db][3] * inv) << 48);
      *(uint64_t*)&ctx[rowoff + db * 16 + lg * 4] = pk;
    }
  }
}

// ---------------- host ----------------
extern "C" void kernel_launch(void* const* d_in, const int* in_sizes, int n_in,
                              void* d_out, int out_size, void* d_ws, size_t ws_size,
                              hipStream_t stream) {
  (void)in_sizes; (void)n_in; (void)out_size; (void)ws_size;
  const float* hs  = (const float*)d_in[0];
  const int*   pos = (const int*)d_in[1];
  const float* lf1 = (const float*)d_in[2];
  const float* lf2 = (const float*)d_in[3];
  const float* Wqk = (const float*)d_in[4];
  const float* Wv  = (const float*)d_in[5];
  const float* Wo  = (const float*)d_in[6];
  const float* c1w = (const float*)d_in[7];
  const float* c1b = (const float*)d_in[8];
  const float* c2w = (const float*)d_in[9];
  const float* c2b = (const float*)d_in[10];
  const float* lnw = (const float*)d_in[11];
  float* out = (float*)d_out;
  char*  ws  = (char*)d_ws;

  bf16* wvB   = (bf16*)(ws + OFF_WV);
  bf16* wqkB  = (bf16*)(ws + OFF_WQK);
  bf16* woB   = (bf16*)(ws + OFF_WO);
  bf16* w1B   = (bf16*)(ws + OFF_W1);
  bf16* w2B   = (bf16*)(ws + OFF_W2);
  bf16* hsB   = (bf16*)(ws + OFF_HS);
  bf16* xprB  = (bf16*)(ws + OFF_XPR);
  bf16* o1B   = (bf16*)(ws + OFF_O1);
  bf16* o1pB  = (bf16*)(ws + OFF_O1P);
  float* o2F  = (float*)(ws + OFF_O2);
  bf16* lfB   = (bf16*)(ws + OFF_LF);
  bf16* vtB   = (bf16*)(ws + OFF_VT);
  float* cosT = (float*)(ws + OFF_COS);
  float* sinT = (float*)(ws + OFF_SIN);
  bf16* qB    = (bf16*)(ws + OFF_Q);
  bf16* kB    = (bf16*)(ws + OFF_K);
  bf16* ctxB  = (bf16*)(ws + OFF_CTX);

  // YaRN inv_freq on host (fp64), matching the reference exactly
  InvF f;
  {
    const double base = 10000.0, scale = 2.0;
    const int hd = HDc;
    auto corr = [&](double nr) {
      return hd * log(8192.0 / (nr * 2.0 * M_PI)) / (2.0 * log(base));
    };
    double low = floor(corr(32.0)); if (low < 0) low = 0;
    double high = ceil(corr(1.0));  if (high > hd - 1) high = hd - 1;
    double hi = (low == high) ? high + 0.001 : high;
    for (int i = 0; i < 32; ++i) {
      double inv = 1.0 / pow(base, (2.0 * i) / hd);
      double ramp = ((double)i - low) / (hi - low);
      ramp = ramp < 0.0 ? 0.0 : (ramp > 1.0 ? 1.0 : ramp);
      double mask = 1.0 - ramp;
      f.v[i] = inv / ((1.0 - mask) * scale + mask);
    }
    f.mscale = 0.1 * log(scale) + 1.0;
  }

  // conversions / repacks / tables
  k_cvt<<<(Hc * Hc + 255) / 256, 256, 0, stream>>>(Wv, wvB, Hc * Hc);
  k_cvt<<<(2 * Hc * Hc + 255) / 256, 256, 0, stream>>>(Wqk, wqkB, 2 * Hc * Hc);
  k_cvt<<<(Hc * Hc + 255) / 256, 256, 0, stream>>>(Wo, woB, Hc * Hc);
  k_repack1<<<((Hc / 2) * 2 * Hc + 255) / 256, 256, 0, stream>>>(c1w, w1B);
  k_repack2<<<(Hc * Hc + 255) / 256, 256, 0, stream>>>(c2w, w2B);
  k_cvt_hs<<<(Mc * Hc + 255) / 256, 256, 0, stream>>>(hs, lf1, hsB, xprB);
  k_prefill_o1p<<<(Bc * (Hc / 2) + 255) / 256, 256, 0, stream>>>(lf2, o1pB);
  k_costab<<<(MAXPOS * HDc + 255) / 256, 256, 0, stream>>>(f, cosT, sinT);

  // conv1: o1 = [xprev|x] @ w1cat^T + b1  (gemm8 128x128, grid 8x32 = 1/CU)
  gemm8<1, 128, 128><<<dim3((Hc / 2) / 128, Mc / 128), 512, 0, stream>>>(
      xprB, hsB, Hc, w1B, 2 * Hc, Hc / 2, o1B, c1b, nullptr,
      nullptr, nullptr, nullptr, o1pB);
  // v^T: C'[hd][(b,s)] = Wv @ hs^T
  gemm8<5, 256, 128><<<dim3(Mc / 128, Hc / 256), 512, 0, stream>>>(
      wvB, wvB, Hc, hsB, Hc, Mc, vtB, nullptr, nullptr, nullptr, nullptr, nullptr, nullptr);
  // conv2: o2res = [o1prev|o1] @ w2cat^T + b2 + hidden  (fp32)
  gemm8<2, 256, 128><<<dim3(Hc / 128, Mc / 256), 512, 0, stream>>>(
      o1pB, o1B, Hc / 2, w2B, Hc, Hc, o2F, c2b, hs, nullptr, nullptr, nullptr, nullptr);
  // lf = rmsnorm(o2res) * ln_w
  k_rmsnorm<<<Mc, 256, 0, stream>>>(o2F, lnw, lfB);
  // qk = lf @ Wqk^T with fused RoPE -> q (pre-scaled, exp2 domain), k
  gemm8<6, 256, 256><<<dim3((2 * Hc) / 256, Mc / 256), 512, 0, stream>>>(
      lfB, lfB, Hc, wqkB, Hc, 2 * Hc, qB, nullptr, nullptr, pos, cosT, sinT, kB);
  // causal flash attention -> ctx (b,s,h*64+d)
  k_attn<<<dim3(64, 8), 512, 0, stream>>>(qB, kB, vtB, ctxB);
  // out = ctx @ Wo^T  (fp32)
  gemm8<4, 256, 128><<<dim3(Hc / 128, Mc / 256), 512, 0, stream>>>(
      ctxB, ctxB, Hc, woB, Hc, Hc, out, nullptr, nullptr, nullptr, nullptr, nullptr, nullptr);
}

// Round 14
// 451.707 us; speedup vs baseline: 1.2513x; 1.2513x over previous
//
#include <hip/hip_runtime.h>
#include <hip/hip_bf16.h>
#include <math.h>
#include <stdint.h>

typedef __hip_bfloat16 bf16;
using f32x4 = __attribute__((ext_vector_type(4))) float;
using s16x8 = __attribute__((ext_vector_type(8))) short;

constexpr int Bc = 2, Sc = 2048, Hc = 2048, NHc = 32, HDc = 64;
constexpr int Mc = Bc * Sc;      // 4096 rows
constexpr int MAXPOS = 8192;

// ---------------- workspace layout (bytes) ----------------
constexpr size_t OFF_WV  = 0;
constexpr size_t OFF_WQK = OFF_WV  + (size_t)Hc * Hc * 2;
constexpr size_t OFF_WO  = OFF_WQK + (size_t)2 * Hc * Hc * 2;
constexpr size_t OFF_W1  = OFF_WO  + (size_t)Hc * Hc * 2;
constexpr size_t OFF_W2  = OFF_W1  + (size_t)(Hc/2) * (2*Hc) * 2;
constexpr size_t OFF_HS  = OFF_W2  + (size_t)Hc * Hc * 2;
constexpr size_t OFF_XPR = OFF_HS  + (size_t)Mc * Hc * 2;
constexpr size_t OFF_O1  = OFF_XPR + (size_t)Mc * Hc * 2;
constexpr size_t OFF_O1P = OFF_O1  + (size_t)Mc * (Hc/2) * 2;
constexpr size_t OFF_O2  = OFF_O1P + (size_t)Mc * (Hc/2) * 2;
constexpr size_t OFF_LF  = OFF_O2  + (size_t)Mc * Hc * 4;
constexpr size_t OFF_VT  = OFF_LF  + (size_t)Mc * Hc * 2;
constexpr size_t OFF_COS = OFF_VT  + (size_t)Mc * Hc * 2;
constexpr size_t OFF_SIN = OFF_COS + (size_t)MAXPOS * HDc * 4;
constexpr size_t OFF_Q   = OFF_XPR;  // q over xprev
constexpr size_t OFF_K   = OFF_HS;   // k over hs
constexpr size_t OFF_CTX = OFF_O1;   // ctx over o1+o1prev

// ---------------- helpers ----------------
__device__ __forceinline__ f32x4 mfma16(s16x8 a, s16x8 b, f32x4 c) {
  return __builtin_amdgcn_mfma_f32_16x16x32_bf16(a, b, c, 0, 0, 0);
}
__device__ __forceinline__ void gload16(const bf16* g, bf16* l) {
  __builtin_amdgcn_global_load_lds(
      (__attribute__((address_space(1))) void*)g,
      (__attribute__((address_space(3))) void*)l, 16, 0, 0);
}
__device__ __forceinline__ uint16_t bfbits(float x) {
  union { bf16 h; uint16_t u; } v; v.h = __float2bfloat16(x); return v.u;
}
__device__ __forceinline__ uint32_t pkbf(float a, float b) {
  return (uint32_t)bfbits(a) | ((uint32_t)bfbits(b) << 16);
}
__device__ __forceinline__ void block_bar() {
  asm volatile("" ::: "memory");
  __builtin_amdgcn_s_barrier();
  asm volatile("" ::: "memory");
}
template <int N> __device__ __forceinline__ void vm_wait() {
  if constexpr (N == 0)      asm volatile("s_waitcnt vmcnt(0)" ::: "memory");
  else if constexpr (N == 2) asm volatile("s_waitcnt vmcnt(2)" ::: "memory");
  else if constexpr (N == 3) asm volatile("s_waitcnt vmcnt(3)" ::: "memory");
  else if constexpr (N == 4) asm volatile("s_waitcnt vmcnt(4)" ::: "memory");
  else if constexpr (N == 6) asm volatile("s_waitcnt vmcnt(6)" ::: "memory");
  else if constexpr (N == 8) asm volatile("s_waitcnt vmcnt(8)" ::: "memory");
}

// ---------------- small conversion kernels ----------------
__global__ void k_cvt(const float* __restrict__ in, bf16* __restrict__ out, int n) {
  int i = blockIdx.x * 256 + threadIdx.x;
  if (i < n) out[i] = __float2bfloat16(in[i]);
}

__global__ void k_cvt_hs(const float* __restrict__ hs, const float* __restrict__ lf1,
                         bf16* __restrict__ hsb, bf16* __restrict__ xprev) {
  int i = blockIdx.x * 256 + threadIdx.x;      // over M*H
  if (i >= Mc * Hc) return;
  float v = hs[i];
  bf16 b = __float2bfloat16(v);
  hsb[i] = b;
  int row = i >> 11, col = i & (Hc - 1);
  int s = row & (Sc - 1), bb = row >> 11;
  if (s + 1 < Sc) xprev[i + Hc] = b;
  if (s == 0)     xprev[i] = __float2bfloat16(lf1[bb * Hc + col]);
}

__global__ void k_repack1(const float* __restrict__ w, bf16* __restrict__ out) {
  int i = blockIdx.x * 256 + threadIdx.x;      // 1024*4096
  if (i >= (Hc/2) * 2 * Hc) return;
  int oc = i >> 12, k = i & 4095;
  int ic = k & (Hc - 1), t = k >> 11;
  out[i] = __float2bfloat16(w[((size_t)oc * Hc + ic) * 2 + t]);
}
__global__ void k_repack2(const float* __restrict__ w, bf16* __restrict__ out) {
  int i = blockIdx.x * 256 + threadIdx.x;      // 2048*2048
  if (i >= Hc * Hc) return;
  int c = i >> 11, k = i & (Hc - 1);
  int oc = k & (Hc/2 - 1), t = k >> 10;
  out[i] = __float2bfloat16(w[((size_t)c * (Hc/2) + oc) * 2 + t]);
}

__global__ void k_prefill_o1p(const float* __restrict__ lf2, bf16* __restrict__ o1p) {
  int i = blockIdx.x * 256 + threadIdx.x;      // B * H/2
  if (i >= Bc * (Hc/2)) return;
  int b = i >> 10, n = i & (Hc/2 - 1);
  o1p[(size_t)b * Sc * (Hc/2) + n] = __float2bfloat16(lf2[i]);
}

struct InvF { double v[32]; double mscale; };

__global__ void k_costab(InvF f, float* __restrict__ ct, float* __restrict__ st) {
  int i = blockIdx.x * 256 + threadIdx.x;      // MAXPOS*64
  if (i >= MAXPOS * HDc) return;
  int p = i >> 6, d = i & 63;
  double ang = (double)p * f.v[d & 31];
  ct[i] = (float)(cos(ang) * f.mscale);
  st[i] = (float)(sin(ang) * f.mscale);
}

// ---------------- RMSNorm (block per row) ----------------
__global__ __launch_bounds__(256) void k_rmsnorm(const float* __restrict__ x,
                                                 const float* __restrict__ w,
                                                 bf16* __restrict__ out) {
  __shared__ float red[4];
  int row = blockIdx.x;
  const float* xr = x + (size_t)row * Hc;
  float ss = 0.f;
  for (int c = threadIdx.x; c < Hc; c += 256) { float v = xr[c]; ss += v * v; }
  for (int off = 32; off; off >>= 1) ss += __shfl_down(ss, off, 64);
  if ((threadIdx.x & 63) == 0) red[threadIdx.x >> 6] = ss;
  __syncthreads();
  float sc = rsqrtf((red[0] + red[1] + red[2] + red[3]) / Hc + 1e-6f);
  for (int c = threadIdx.x; c < Hc; c += 256)
    out[(size_t)row * Hc + c] = __float2bfloat16(xr[c] * sc * w[c]);
}

// ---------------- triple-buffered counted-vmcnt GEMM (512 thr, 8 waves) ---
// C[M,N] = A[M,K] @ W[N,K]^T. 3 LDS slots; stage tile t+2 while computing t;
// raw s_barrier + counted vmcnt (never 0 in main loop). Paired-row LDS pack
// with XOR chunk swizzle (rule #21). Rect XCD swizzle.
// EPI: 1 conv1 (+bias, dual store via out2) | 2 +bias+resid fp32 | 4 fp32
//      | 5 v^T store | 6 fused-RoPE q/k writer (BN=256 only)
template <int EPI, int BM, int BN>
__global__ __launch_bounds__(512, 2) void gemm8(
    const bf16* __restrict__ A0, const bf16* __restrict__ A1, int Ksplit,
    const bf16* __restrict__ Bw, int K, int N, void* __restrict__ Cout,
    const float* __restrict__ bias, const float* __restrict__ resid,
    const int* __restrict__ pos, const float* __restrict__ ct,
    const float* __restrict__ st, bf16* __restrict__ out2) {
  constexpr int L = (BM + BN) / 128;            // gload16 per thread per tile
  constexpr int TILE = (BM + BN) * 32;
  constexpr int MF = (BM == 256) ? ((BN == 256) ? 8 : 4) : 4;
  constexpr int NF = (BN == 256) ? 4 : ((BM == 256) ? 4 : 2);
  __shared__ __align__(16) bf16 lds[3][TILE];
  const int tid = threadIdx.x;
  const int w = tid >> 6, l = tid & 63;
  const int lrow = l & 15, lg = l >> 4;
  const int wm = (BM == 256) ? ((BN == 256) ? (w >> 2) * 128 : (w & 3) * 64)
                             : (w >> 2) * 64;
  const int wn = (BM == 256) ? ((BN == 256) ? (w & 3) * 64 : (w >> 2) * 64)
                             : (w & 3) * 32;
  // rect XCD swizzle: XCD c gets a (gx/4)x(gy/2) block rectangle
  const int gx = gridDim.x;
  const int lin = blockIdx.y * gx + blockIdx.x;
  const int cx = gx >> 2, cy = gridDim.y >> 1;
  const int c = lin & 7, idx = lin >> 3;
  const int bn = (c & 3) * cx + idx % cx;
  const int bm = (c >> 2) * cy + idx / cx;

  auto ld1 = [&](const bf16* srcbase, size_t stride, bf16* ldst, int ci) {
    const int pr = ci >> 3, rem = ci & 7;
    const int r = pr * 2 + (rem >> 2), g = (rem & 3) ^ (pr & 3);
    gload16(srcbase + (size_t)r * stride + g * 8, ldst + ci * 8);
  };
  auto stage = [&](int kt, int slot) {
    const int kcol = kt * 32;
    const bf16* Au; int kc;
    if (kcol < Ksplit) { Au = A0; kc = kcol; } else { Au = A1; kc = kcol - Ksplit; }
    const bf16* As_ = Au + (size_t)bm * BM * Ksplit + kc;
    bf16* ldsA = lds[slot];
    ld1(As_, Ksplit, ldsA, tid);
    if constexpr (BM == 256) ld1(As_, Ksplit, ldsA, tid + 512);
    const bf16* Bs_ = Bw + (size_t)bn * BN * K + kcol;
    bf16* ldsB = lds[slot] + BM * 32;
    ld1(Bs_, K, ldsB, tid);
    if constexpr (BN == 256) ld1(Bs_, K, ldsB, tid + 512);
  };
  auto frag = [&](const bf16* base, int r) -> s16x8 {
    const int s = ((r >> 1) << 3) + ((r & 1) << 2) + (lg ^ ((r >> 1) & 3));
    return *(const s16x8*)(base + s * 8);
  };

  f32x4 acc[MF][NF] = {};
  const int nkt = K / 32;
  stage(0, 0);
  stage(1, 1);
  for (int t = 0; t < nkt; ++t) {
    if (t + 2 < nkt) { stage(t + 2, (t + 2) % 3); vm_wait<2 * L>(); }
    else if (t + 1 < nkt) { vm_wait<L>(); }
    else { vm_wait<0>(); }
    block_bar();
    const bf16* Asl = lds[t % 3];
    const bf16* Bsl = Asl + BM * 32;
    s16x8 af[MF], bfr[NF];
#pragma unroll
    for (int m = 0; m < MF; ++m) af[m] = frag(Asl, wm + m * 16 + lrow);
#pragma unroll
    for (int n = 0; n < NF; ++n) bfr[n] = frag(Bsl, wn + n * 16 + lrow);
    __builtin_amdgcn_s_setprio(1);
#pragma unroll
    for (int m = 0; m < MF; ++m)
#pragma unroll
      for (int n = 0; n < NF; ++n)
        acc[m][n] = mfma16(af[m], bfr[n], acc[m][n]);
    __builtin_amdgcn_s_setprio(0);
    block_bar();
  }
  if constexpr (EPI == 6) {
    // fused RoPE: wave's 64-col window = one (head, q|k) half. Pairs are
    // acc[m][n] (d) / acc[m][n+2] (d+32), n in {0,1}.
    const int gcol0 = bn * BN + wn;            // wave-uniform
    const int h = gcol0 >> 7, half = (gcol0 >> 6) & 1;
    bf16* outp = half ? out2 : (bf16*)Cout;
    const float qsc = half ? 1.0f : 0.125f * 1.44269504088896f;
#pragma unroll
    for (int m = 0; m < MF; ++m)
#pragma unroll
      for (int r = 0; r < 4; ++r) {
        const int grow = bm * BM + wm + m * 16 + lg * 4 + r;
        const int p = pos[grow];
        const int bb = grow >> 11, s = grow & (Sc - 1);
        bf16* rowp = outp + ((size_t)(bb * NHc + h) * Sc + s) * 64;
#pragma unroll
        for (int n = 0; n < 2; ++n) {
          const int dd = n * 16 + lrow;
          const float c0 = ct[p * 64 + dd],      s0 = st[p * 64 + dd];
          const float c1 = ct[p * 64 + 32 + dd], s1 = st[p * 64 + 32 + dd];
          const float v0 = acc[m][n][r], v1 = acc[m][n + 2][r];
          rowp[dd]      = __float2bfloat16((v0 * c0 - v1 * s0) * qsc);
          rowp[dd + 32] = __float2bfloat16((v1 * c1 + v0 * s1) * qsc);
        }
      }
  } else {
#pragma unroll
    for (int m = 0; m < MF; ++m)
#pragma unroll
      for (int n = 0; n < NF; ++n)
#pragma unroll
        for (int r = 0; r < 4; ++r) {
          const int grow = bm * BM + wm + m * 16 + lg * 4 + r;
          const int gcol = bn * BN + wn + n * 16 + lrow;
          float v = acc[m][n][r];
          if constexpr (EPI == 1) {
            v += bias[gcol];
            bf16 bv = __float2bfloat16(v);
            ((bf16*)Cout)[(size_t)grow * N + gcol] = bv;
            if ((grow & (Sc - 1)) != Sc - 1) out2[(size_t)(grow + 1) * N + gcol] = bv;
          } else if constexpr (EPI == 2) {
            v += bias[gcol] + resid[(size_t)grow * N + gcol];
            ((float*)Cout)[(size_t)grow * N + gcol] = v;
          } else if constexpr (EPI == 5) {
            const int b = gcol >> 11, s = gcol & (Sc - 1);
            ((bf16*)Cout)[((size_t)(b * Hc + grow)) * Sc + s] = __float2bfloat16(v);
          } else {
            ((float*)Cout)[(size_t)grow * N + gcol] = v;
          }
        }
  }
}

// ---------------- causal flash attention (block-staged K/V, KVBLK=64) -----
// Round-12 proven version: 256 threads / 4 waves, 2-slot double buffer,
// __syncthreads protocol, 53KB LDS -> 3 blocks/CU, VGPR 128. The 8-wave
// merged variant spilled (launch_bounds cap 64 VGPR -> 300MB scratch, 2.3x).
__global__ __launch_bounds__(256) void k_attn(const bf16* __restrict__ Q,
                                              const bf16* __restrict__ Kg,
                                              const bf16* __restrict__ Vt,
                                              bf16* __restrict__ ctx) {
  __shared__ __align__(16) bf16 Ks[2][64 * 64];
  __shared__ __align__(16) bf16 Vs[2][64 * 64];
  __shared__ __align__(16) uint32_t Pl[4][2][2][16][20];
  const int tid = threadIdx.x;
  const int w = tid >> 6, l = tid & 63;
  const int lrow = l & 15, lg = l >> 4, lk = lg * 8;
  const int bh = blockIdx.x;
  const int tile = blockIdx.y;
  const bf16* Qp = Q  + (size_t)bh * Sc * HDc;
  const bf16* Kp = Kg + (size_t)bh * Sc * HDc;
  const bf16* Vp = Vt + (size_t)bh * HDc * Sc;
  const int b = bh >> 5, h = bh & 31;
  const s16x8 ones8 = {16256, 16256, 16256, 16256, 16256, 16256, 16256, 16256};

  const int srow0 = tid >> 3, schunk = tid & 7;

  for (int pass = 0; pass < 2; ++pass) {
    const int base = (pass == 0) ? tile * 128 : (Sc - 128 - tile * 128);
    const int q0 = base + w * 32;
    const int NT = base / 64 + 2;

    s16x8 qa[2][2];
#pragma unroll
    for (int m = 0; m < 2; ++m)
#pragma unroll
      for (int hf = 0; hf < 2; ++hf)
        qa[m][hf] = *(const s16x8*)&Qp[(size_t)(q0 + m * 16 + lrow) * 64 + hf * 32 + lk];

    f32x4 o[2][4] = {};
    f32x4 lsf[2] = {};
    float mx[2] = {-1e30f, -1e30f};

    {
      gload16(Kp + (size_t)srow0 * 64 + ((schunk ^ (srow0 & 7)) << 3), &Ks[0][tid * 8]);
      gload16(Kp + (size_t)(32 + srow0) * 64 + ((schunk ^ ((32 + srow0) & 7)) << 3),
              &Ks[0][2048 + tid * 8]);
      gload16(Vp + (size_t)srow0 * Sc + ((schunk ^ (srow0 & 7)) << 3), &Vs[0][tid * 8]);
      gload16(Vp + (size_t)(32 + srow0) * Sc + ((schunk ^ ((32 + srow0) & 7)) << 3),
              &Vs[0][2048 + tid * 8]);
    }
    __syncthreads();

    for (int t = 0; t < NT; ++t) {
      const int cur = t & 1;
      const int kv0 = t * 64;
      if (t + 1 < NT) {
        const int nkv = kv0 + 64;
        const int nb = cur ^ 1;
        gload16(Kp + (size_t)(nkv + srow0) * 64 + ((schunk ^ (srow0 & 7)) << 3),
                &Ks[nb][tid * 8]);
        gload16(Kp + (size_t)(nkv + 32 + srow0) * 64 + ((schunk ^ ((32 + srow0) & 7)) << 3),
                &Ks[nb][2048 + tid * 8]);
        gload16(Vp + (size_t)srow0 * Sc + nkv + ((schunk ^ (srow0 & 7)) << 3),
                &Vs[nb][tid * 8]);
        gload16(Vp + (size_t)(32 + srow0) * Sc + nkv + ((schunk ^ ((32 + srow0) & 7)) << 3),
                &Vs[nb][2048 + tid * 8]);
      }
      if (kv0 <= q0) {
        s16x8 kc[8], vc[4][2];
#pragma unroll
        for (int c = 0; c < 4; ++c)
#pragma unroll
          for (int hf = 0; hf < 2; ++hf) {
            const int row = c * 16 + lrow;
            kc[c * 2 + hf] =
                *(const s16x8*)&Ks[cur][row * 64 + (((hf << 2) + lg) ^ (row & 7)) * 8];
          }
#pragma unroll
        for (int db = 0; db < 4; ++db)
#pragma unroll
          for (int kh = 0; kh < 2; ++kh) {
            const int row = db * 16 + lrow;
            vc[db][kh] =
                *(const s16x8*)&Vs[cur][row * 64 + (((kh << 2) + lg) ^ (row & 7)) * 8];
          }
        const bool lastit = (kv0 + 64 > q0);

#pragma unroll
        for (int m = 0; m < 2; ++m) {
          f32x4 s[4];
          __builtin_amdgcn_s_setprio(1);
#pragma unroll
          for (int c = 0; c < 4; ++c) {
            f32x4 z = {};
            z = mfma16(kc[c * 2], qa[m][0], z);
            z = mfma16(kc[c * 2 + 1], qa[m][1], z);
            s[c] = z;
          }
          __builtin_amdgcn_s_setprio(0);

          if (lastit) {
            const int qq = q0 + m * 16 + lrow;
#pragma unroll
            for (int c = 0; c < 4; ++c)
#pragma unroll
              for (int r = 0; r < 4; ++r)
                if (kv0 + c * 16 + lg * 4 + r > qq) s[c][r] = -1e30f;
          }
          float t16 = fmaxf(
              fmaxf(fmaxf(fmaxf(s[0][0], s[0][1]), fmaxf(s[0][2], s[0][3])),
                    fmaxf(fmaxf(s[1][0], s[1][1]), fmaxf(s[1][2], s[1][3]))),
              fmaxf(fmaxf(fmaxf(s[2][0], s[2][1]), fmaxf(s[2][2], s[2][3])),
                    fmaxf(fmaxf(s[3][0], s[3][1]), fmaxf(s[3][2], s[3][3]))));
          if (!__all(t16 <= mx[m] + 8.0f)) {
            t16 = fmaxf(t16, __shfl_xor(t16, 16, 64));
            t16 = fmaxf(t16, __shfl_xor(t16, 32, 64));
            const float mnew = fmaxf(mx[m], t16);
            const float sold = __builtin_amdgcn_exp2f(mx[m] - mnew);
            mx[m] = mnew;
            lsf[m] *= sold;
#pragma unroll
            for (int db = 0; db < 4; ++db) o[m][db] *= sold;
          }
          float p[4][4];
#pragma unroll
          for (int c = 0; c < 4; ++c)
#pragma unroll
            for (int r = 0; r < 4; ++r)
              p[c][r] = __builtin_amdgcn_exp2f(s[c][r] - mx[m]);
#pragma unroll
          for (int kh = 0; kh < 2; ++kh) {
            *(uint64_t*)&Pl[w][m][kh][lrow][lg * 2] =
                (uint64_t)pkbf(p[kh * 2][0], p[kh * 2][1]) |
                ((uint64_t)pkbf(p[kh * 2][2], p[kh * 2][3]) << 32);
            *(uint64_t*)&Pl[w][m][kh][lrow][8 + lg * 2] =
                (uint64_t)pkbf(p[kh * 2 + 1][0], p[kh * 2 + 1][1]) |
                ((uint64_t)pkbf(p[kh * 2 + 1][2], p[kh * 2 + 1][3]) << 32);
          }
          const s16x8 pb0 = *(const s16x8*)&Pl[w][m][0][lrow][lg * 4];
          const s16x8 pb1 = *(const s16x8*)&Pl[w][m][1][lrow][lg * 4];
          __builtin_amdgcn_s_setprio(1);
#pragma unroll
          for (int db = 0; db < 4; ++db) o[m][db] = mfma16(vc[db][0], pb0, o[m][db]);
          lsf[m] = mfma16(ones8, pb0, lsf[m]);
#pragma unroll
          for (int db = 0; db < 4; ++db) o[m][db] = mfma16(vc[db][1], pb1, o[m][db]);
          lsf[m] = mfma16(ones8, pb1, lsf[m]);
          __builtin_amdgcn_s_setprio(0);
        }
      }
      __syncthreads();
    }
#pragma unroll
    for (int m = 0; m < 2; ++m) {
      const float inv = 1.0f / lsf[m][0];
      const int qrow = q0 + m * 16 + lrow;
      const size_t rowoff = ((size_t)(b * Sc + qrow)) * Hc + h * 64;
#pragma unroll
      for (int db = 0; db < 4; ++db) {
        uint64_t pk = (uint64_t)bfbits(o[m][db][0] * inv) |
                      ((uint64_t)bfbits(o[m][db][1] * inv) << 16) |
                      ((uint64_t)bfbits(o[m][db][2] * inv) << 32) |
                      ((uint64_t)bfbits(o[m][db][3] * inv) << 48);
        *(uint64_t*)&ctx[rowoff + db * 16 + lg * 4] = pk;
      }
    }
    __syncthreads();
  }
}

// ---------------- host ----------------
extern "C" void kernel_launch(void* const* d_in, const int* in_sizes, int n_in,
                              void* d_out, int out_size, void* d_ws, size_t ws_size,
                              hipStream_t stream) {
  (void)in_sizes; (void)n_in; (void)out_size; (void)ws_size;
  const float* hs  = (const float*)d_in[0];
  const int*   pos = (const int*)d_in[1];
  const float* lf1 = (const float*)d_in[2];
  const float* lf2 = (const float*)d_in[3];
  const float* Wqk = (const float*)d_in[4];
  const float* Wv  = (const float*)d_in[5];
  const float* Wo  = (const float*)d_in[6];
  const float* c1w = (const float*)d_in[7];
  const float* c1b = (const float*)d_in[8];
  const float* c2w = (const float*)d_in[9];
  const float* c2b = (const float*)d_in[10];
  const float* lnw = (const float*)d_in[11];
  float* out = (float*)d_out;
  char*  ws  = (char*)d_ws;

  bf16* wvB   = (bf16*)(ws + OFF_WV);
  bf16* wqkB  = (bf16*)(ws + OFF_WQK);
  bf16* woB   = (bf16*)(ws + OFF_WO);
  bf16* w1B   = (bf16*)(ws + OFF_W1);
  bf16* w2B   = (bf16*)(ws + OFF_W2);
  bf16* hsB   = (bf16*)(ws + OFF_HS);
  bf16* xprB  = (bf16*)(ws + OFF_XPR);
  bf16* o1B   = (bf16*)(ws + OFF_O1);
  bf16* o1pB  = (bf16*)(ws + OFF_O1P);
  float* o2F  = (float*)(ws + OFF_O2);
  bf16* lfB   = (bf16*)(ws + OFF_LF);
  bf16* vtB   = (bf16*)(ws + OFF_VT);
  float* cosT = (float*)(ws + OFF_COS);
  float* sinT = (float*)(ws + OFF_SIN);
  bf16* qB    = (bf16*)(ws + OFF_Q);
  bf16* kB    = (bf16*)(ws + OFF_K);
  bf16* ctxB  = (bf16*)(ws + OFF_CTX);

  // YaRN inv_freq on host (fp64), matching the reference exactly
  InvF f;
  {
    const double base = 10000.0, scale = 2.0;
    const int hd = HDc;
    auto corr = [&](double nr) {
      return hd * log(8192.0 / (nr * 2.0 * M_PI)) / (2.0 * log(base));
    };
    double low = floor(corr(32.0)); if (low < 0) low = 0;
    double high = ceil(corr(1.0));  if (high > hd - 1) high = hd - 1;
    double hi = (low == high) ? high + 0.001 : high;
    for (int i = 0; i < 32; ++i) {
      double inv = 1.0 / pow(base, (2.0 * i) / hd);
      double ramp = ((double)i - low) / (hi - low);
      ramp = ramp < 0.0 ? 0.0 : (ramp > 1.0 ? 1.0 : ramp);
      double mask = 1.0 - ramp;
      f.v[i] = inv / ((1.0 - mask) * scale + mask);
    }
    f.mscale = 0.1 * log(scale) + 1.0;
  }

  // conversions / repacks / tables
  k_cvt<<<(Hc * Hc + 255) / 256, 256, 0, stream>>>(Wv, wvB, Hc * Hc);
  k_cvt<<<(2 * Hc * Hc + 255) / 256, 256, 0, stream>>>(Wqk, wqkB, 2 * Hc * Hc);
  k_cvt<<<(Hc * Hc + 255) / 256, 256, 0, stream>>>(Wo, woB, Hc * Hc);
  k_repack1<<<((Hc / 2) * 2 * Hc + 255) / 256, 256, 0, stream>>>(c1w, w1B);
  k_repack2<<<(Hc * Hc + 255) / 256, 256, 0, stream>>>(c2w, w2B);
  k_cvt_hs<<<(Mc * Hc + 255) / 256, 256, 0, stream>>>(hs, lf1, hsB, xprB);
  k_prefill_o1p<<<(Bc * (Hc / 2) + 255) / 256, 256, 0, stream>>>(lf2, o1pB);
  k_costab<<<(MAXPOS * HDc + 255) / 256, 256, 0, stream>>>(f, cosT, sinT);

  // conv1: o1 = [xprev|x] @ w1cat^T + b1  (gemm8 128x128, grid 8x32 = 1/CU)
  gemm8<1, 128, 128><<<dim3((Hc / 2) / 128, Mc / 128), 512, 0, stream>>>(
      xprB, hsB, Hc, w1B, 2 * Hc, Hc / 2, o1B, c1b, nullptr,
      nullptr, nullptr, nullptr, o1pB);
  // v^T: C'[hd][(b,s)] = Wv @ hs^T
  gemm8<5, 256, 128><<<dim3(Mc / 128, Hc / 256), 512, 0, stream>>>(
      wvB, wvB, Hc, hsB, Hc, Mc, vtB, nullptr, nullptr, nullptr, nullptr, nullptr, nullptr);
  // conv2: o2res = [o1prev|o1] @ w2cat^T + b2 + hidden  (fp32)
  gemm8<2, 256, 128><<<dim3(Hc / 128, Mc / 256), 512, 0, stream>>>(
      o1pB, o1B, Hc / 2, w2B, Hc, Hc, o2F, c2b, hs, nullptr, nullptr, nullptr, nullptr);
  // lf = rmsnorm(o2res) * ln_w
  k_rmsnorm<<<Mc, 256, 0, stream>>>(o2F, lnw, lfB);
  // qk = lf @ Wqk^T with fused RoPE -> q (pre-scaled, exp2 domain), k
  gemm8<6, 256, 256><<<dim3((2 * Hc) / 256, Mc / 256), 512, 0, stream>>>(
      lfB, lfB, Hc, wqkB, Hc, 2 * Hc, qB, nullptr, nullptr, pos, cosT, sinT, kB);
  // causal flash attention -> ctx (b,s,h*64+d)
  k_attn<<<dim3(64, 8), 256, 0, stream>>>(qB, kB, vtB, ctxB);
  // out = ctx @ Wo^T  (fp32)
  gemm8<4, 256, 128><<<dim3(Hc / 128, Mc / 256), 512, 0, stream>>>(
      ctxB, ctxB, Hc, woB, Hc, Hc, out, nullptr, nullptr, nullptr, nullptr, nullptr, nullptr);
}

// Round 15
// 405.548 us; speedup vs baseline: 1.3938x; 1.1138x over previous
//
#include <hip/hip_runtime.h>
#include <hip/hip_bf16.h>
#include <math.h>
#include <stdint.h>

typedef __hip_bfloat16 bf16;
using f32x4 = __attribute__((ext_vector_type(4))) float;
using s16x8 = __attribute__((ext_vector_type(8))) short;

constexpr int Bc = 2, Sc = 2048, Hc = 2048, NHc = 32, HDc = 64;
constexpr int Mc = Bc * Sc;      // 4096 rows
constexpr int MAXPOS = 8192;

// ---------------- workspace layout (bytes) ----------------
constexpr size_t OFF_WV  = 0;
constexpr size_t OFF_WQK = OFF_WV  + (size_t)Hc * Hc * 2;
constexpr size_t OFF_WO  = OFF_WQK + (size_t)2 * Hc * Hc * 2;
constexpr size_t OFF_W1  = OFF_WO  + (size_t)Hc * Hc * 2;
constexpr size_t OFF_W2  = OFF_W1  + (size_t)(Hc/2) * (2*Hc) * 2;
constexpr size_t OFF_HS  = OFF_W2  + (size_t)Hc * Hc * 2;
constexpr size_t OFF_XPR = OFF_HS  + (size_t)Mc * Hc * 2;
constexpr size_t OFF_O1  = OFF_XPR + (size_t)Mc * Hc * 2;
constexpr size_t OFF_O1P = OFF_O1  + (size_t)Mc * (Hc/2) * 2;
constexpr size_t OFF_O2  = OFF_O1P + (size_t)Mc * (Hc/2) * 2;   // o2res bf16 now
constexpr size_t OFF_LF  = OFF_O2  + (size_t)Mc * Hc * 4;
constexpr size_t OFF_VT  = OFF_LF  + (size_t)Mc * Hc * 2;
constexpr size_t OFF_COS = OFF_VT  + (size_t)Mc * Hc * 2;
constexpr size_t OFF_SIN = OFF_COS + (size_t)MAXPOS * HDc * 4;
constexpr size_t OFF_Q   = OFF_XPR;  // q over xprev
constexpr size_t OFF_K   = OFF_HS;   // k over hs
constexpr size_t OFF_CTX = OFF_O1;   // ctx over o1+o1prev

// ---------------- helpers ----------------
__device__ __forceinline__ f32x4 mfma16(s16x8 a, s16x8 b, f32x4 c) {
  return __builtin_amdgcn_mfma_f32_16x16x32_bf16(a, b, c, 0, 0, 0);
}
__device__ __forceinline__ void gload16(const bf16* g, bf16* l) {
  __builtin_amdgcn_global_load_lds(
      (__attribute__((address_space(1))) void*)g,
      (__attribute__((address_space(3))) void*)l, 16, 0, 0);
}
__device__ __forceinline__ uint16_t bfbits(float x) {
  union { bf16 h; uint16_t u; } v; v.h = __float2bfloat16(x); return v.u;
}
__device__ __forceinline__ float bff(uint16_t u) {
  union { bf16 h; uint16_t u; } v; v.u = u; return __bfloat162float(v.h);
}
__device__ __forceinline__ uint32_t pkbf(float a, float b) {
  return (uint32_t)bfbits(a) | ((uint32_t)bfbits(b) << 16);
}
__device__ __forceinline__ uint64_t pkbf4(float a, float b, float c, float d) {
  return (uint64_t)pkbf(a, b) | ((uint64_t)pkbf(c, d) << 32);
}
__device__ __forceinline__ void block_bar() {
  asm volatile("" ::: "memory");
  __builtin_amdgcn_s_barrier();
  asm volatile("" ::: "memory");
}
template <int N> __device__ __forceinline__ void vm_wait() {
  if constexpr (N == 0)      asm volatile("s_waitcnt vmcnt(0)" ::: "memory");
  else if constexpr (N == 2) asm volatile("s_waitcnt vmcnt(2)" ::: "memory");
  else if constexpr (N == 3) asm volatile("s_waitcnt vmcnt(3)" ::: "memory");
  else if constexpr (N == 4) asm volatile("s_waitcnt vmcnt(4)" ::: "memory");
  else if constexpr (N == 6) asm volatile("s_waitcnt vmcnt(6)" ::: "memory");
  else if constexpr (N == 8) asm volatile("s_waitcnt vmcnt(8)" ::: "memory");
}

struct InvF { double v[32]; double mscale; };

// ---------------- fused preprocessing (1 launch replaces 7) ---------------
// block ranges: [0,16384) wv | [16384,49152) wqk | [49152,65536) wo |
// [65536,81920) repack1 | [81920,98304) repack2 | [98304,100352) costab |
// [100352,100360) prefill o1p
__global__ void k_prep(const float* __restrict__ Wv, const float* __restrict__ Wqk,
                       const float* __restrict__ Wo, const float* __restrict__ c1w,
                       const float* __restrict__ c2w, const float* __restrict__ lf2,
                       InvF f, bf16* __restrict__ wv, bf16* __restrict__ wqk,
                       bf16* __restrict__ wo, bf16* __restrict__ w1,
                       bf16* __restrict__ w2, bf16* __restrict__ o1p,
                       float* __restrict__ ct, float* __restrict__ st) {
  const int blk = blockIdx.x, tid = threadIdx.x;
  if (blk < 16384) {
    const int i = blk * 256 + tid;
    wv[i] = __float2bfloat16(Wv[i]);
  } else if (blk < 49152) {
    const int i = (blk - 16384) * 256 + tid;
    wqk[i] = __float2bfloat16(Wqk[i]);
  } else if (blk < 65536) {
    const int i = (blk - 49152) * 256 + tid;
    wo[i] = __float2bfloat16(Wo[i]);
  } else if (blk < 81920) {
    const int i = (blk - 65536) * 256 + tid;   // 1024*4096
    const int oc = i >> 12, k = i & 4095;
    const int ic = k & (Hc - 1), t = k >> 11;
    w1[i] = __float2bfloat16(c1w[((size_t)oc * Hc + ic) * 2 + t]);
  } else if (blk < 98304) {
    const int i = (blk - 81920) * 256 + tid;   // 2048*2048
    const int c = i >> 11, k = i & (Hc - 1);
    const int oc = k & (Hc / 2 - 1), t = k >> 10;
    w2[i] = __float2bfloat16(c2w[((size_t)c * (Hc / 2) + oc) * 2 + t]);
  } else if (blk < 100352) {
    const int i = (blk - 98304) * 256 + tid;   // MAXPOS*64
    const int p = i >> 6, d = i & 63;
    const double ang = (double)p * f.v[d & 31];
    ct[i] = (float)(cos(ang) * f.mscale);
    st[i] = (float)(sin(ang) * f.mscale);
  } else {
    const int i = (blk - 100352) * 256 + tid;  // B * H/2
    if (i < Bc * (Hc / 2)) {
      const int b = i >> 10, n = i & (Hc / 2 - 1);
      o1p[(size_t)b * Sc * (Hc / 2) + n] = __float2bfloat16(lf2[i]);
    }
  }
}

// hs fp32 -> hs bf16 and xprev (row-shifted, lf1 at s==0), 4 elems/thread
__global__ void k_cvt_hs4(const float* __restrict__ hs, const float* __restrict__ lf1,
                          bf16* __restrict__ hsb, bf16* __restrict__ xprev) {
  const int i = (blockIdx.x * 256 + threadIdx.x) * 4;   // over M*H
  if (i >= Mc * Hc) return;
  const float4 v = *(const float4*)(hs + i);
  const uint64_t pk = pkbf4(v.x, v.y, v.z, v.w);
  *(uint64_t*)(hsb + i) = pk;
  const int row = i >> 11, s = row & (Sc - 1), bb = row >> 11, col = i & (Hc - 1);
  if (s + 1 < Sc) *(uint64_t*)(xprev + i + Hc) = pk;
  if (s == 0) {
    const float4 lv = *(const float4*)(lf1 + bb * Hc + col);
    *(uint64_t*)(xprev + i) = pkbf4(lv.x, lv.y, lv.z, lv.w);
  }
}

// ---------------- RMSNorm (block per row, bf16 input, vectorized) ---------
__global__ __launch_bounds__(256) void k_rmsnorm(const bf16* __restrict__ x,
                                                 const float* __restrict__ w,
                                                 bf16* __restrict__ out) {
  __shared__ float red[4];
  const int row = blockIdx.x, tid = threadIdx.x;
  const s16x8 v = *(const s16x8*)(x + (size_t)row * Hc + tid * 8);
  float fv[8];
  float ss = 0.f;
#pragma unroll
  for (int j = 0; j < 8; ++j) {
    fv[j] = bff((uint16_t)v[j]);
    ss += fv[j] * fv[j];
  }
  for (int off = 32; off; off >>= 1) ss += __shfl_down(ss, off, 64);
  if ((tid & 63) == 0) red[tid >> 6] = ss;
  __syncthreads();
  const float sc = rsqrtf((red[0] + red[1] + red[2] + red[3]) / Hc + 1e-6f);
  const float4 w0 = *(const float4*)(w + tid * 8);
  const float4 w1 = *(const float4*)(w + tid * 8 + 4);
  uint64_t lo = pkbf4(fv[0] * sc * w0.x, fv[1] * sc * w0.y,
                      fv[2] * sc * w0.z, fv[3] * sc * w0.w);
  uint64_t hi = pkbf4(fv[4] * sc * w1.x, fv[5] * sc * w1.y,
                      fv[6] * sc * w1.z, fv[7] * sc * w1.w);
  uint64_t* op = (uint64_t*)(out + (size_t)row * Hc + tid * 8);
  op[0] = lo; op[1] = hi;
}

// ---------------- triple-buffered counted-vmcnt GEMM (512 thr, 8 waves) ---
// EPI: 1 conv1 (+bias, dual store via out2) | 2 +bias + bf16 resid(out2),
//      bf16 out | 4 fp32 | 5 v^T store
template <int EPI, int BM, int BN>
__global__ __launch_bounds__(512, 2) void gemm8(
    const bf16* __restrict__ A0, const bf16* __restrict__ A1, int Ksplit,
    const bf16* __restrict__ Bw, int K, int N, void* __restrict__ Cout,
    const float* __restrict__ bias, bf16* __restrict__ out2) {
  constexpr int L = (BM + BN) / 128;            // gload16 per thread per tile
  constexpr int TILE = (BM + BN) * 32;
  constexpr int MF = (BM == 256) ? 4 : 4;
  constexpr int NF = (BM == 256) ? 4 : 2;
  __shared__ __align__(16) bf16 lds[3][TILE];
  const int tid = threadIdx.x;
  const int w = tid >> 6, l = tid & 63;
  const int lrow = l & 15, lg = l >> 4;
  const int wm = (BM == 256) ? (w & 3) * 64 : (w >> 2) * 64;
  const int wn = (BM == 256) ? (w >> 2) * 64 : (w & 3) * 32;
  // rect XCD swizzle: XCD c gets a (gx/4)x(gy/2) block rectangle
  const int gx = gridDim.x;
  const int lin = blockIdx.y * gx + blockIdx.x;
  const int cx = gx >> 2, cy = gridDim.y >> 1;
  const int c = lin & 7, idx = lin >> 3;
  const int bn = (c & 3) * cx + idx % cx;
  const int bm = (c >> 2) * cy + idx / cx;

  auto ld1 = [&](const bf16* srcbase, size_t stride, bf16* ldst, int ci) {
    const int pr = ci >> 3, rem = ci & 7;
    const int r = pr * 2 + (rem >> 2), g = (rem & 3) ^ (pr & 3);
    gload16(srcbase + (size_t)r * stride + g * 8, ldst + ci * 8);
  };
  auto stage = [&](int kt, int slot) {
    const int kcol = kt * 32;
    const bf16* Au; int kc;
    if (kcol < Ksplit) { Au = A0; kc = kcol; } else { Au = A1; kc = kcol - Ksplit; }
    const bf16* As_ = Au + (size_t)bm * BM * Ksplit + kc;
    bf16* ldsA = lds[slot];
    ld1(As_, Ksplit, ldsA, tid);
    if constexpr (BM == 256) ld1(As_, Ksplit, ldsA, tid + 512);
    const bf16* Bs_ = Bw + (size_t)bn * BN * K + kcol;
    bf16* ldsB = lds[slot] + BM * 32;
    ld1(Bs_, K, ldsB, tid);
    if constexpr (BN == 256) ld1(Bs_, K, ldsB, tid + 512);
  };
  auto frag = [&](const bf16* base, int r) -> s16x8 {
    const int s = ((r >> 1) << 3) + ((r & 1) << 2) + (lg ^ ((r >> 1) & 3));
    return *(const s16x8*)(base + s * 8);
  };

  f32x4 acc[MF][NF] = {};
  const int nkt = K / 32;
  stage(0, 0);
  stage(1, 1);
  for (int t = 0; t < nkt; ++t) {
    if (t + 2 < nkt) { stage(t + 2, (t + 2) % 3); vm_wait<2 * L>(); }
    else if (t + 1 < nkt) { vm_wait<L>(); }
    else { vm_wait<0>(); }
    block_bar();
    const bf16* Asl = lds[t % 3];
    const bf16* Bsl = Asl + BM * 32;
    s16x8 af[MF], bfr[NF];
#pragma unroll
    for (int m = 0; m < MF; ++m) af[m] = frag(Asl, wm + m * 16 + lrow);
#pragma unroll
    for (int n = 0; n < NF; ++n) bfr[n] = frag(Bsl, wn + n * 16 + lrow);
    __builtin_amdgcn_s_setprio(1);
#pragma unroll
    for (int m = 0; m < MF; ++m)
#pragma unroll
      for (int n = 0; n < NF; ++n)
        acc[m][n] = mfma16(af[m], bfr[n], acc[m][n]);
    __builtin_amdgcn_s_setprio(0);
    block_bar();
  }
#pragma unroll
  for (int m = 0; m < MF; ++m)
#pragma unroll
    for (int n = 0; n < NF; ++n)
#pragma unroll
      for (int r = 0; r < 4; ++r) {
        const int grow = bm * BM + wm + m * 16 + lg * 4 + r;
        const int gcol = bn * BN + wn + n * 16 + lrow;
        float v = acc[m][n][r];
        if constexpr (EPI == 1) {
          v += bias[gcol];
          bf16 bv = __float2bfloat16(v);
          ((bf16*)Cout)[(size_t)grow * N + gcol] = bv;
          if ((grow & (Sc - 1)) != Sc - 1) out2[(size_t)(grow + 1) * N + gcol] = bv;
        } else if constexpr (EPI == 2) {
          v += bias[gcol] + __bfloat162float(out2[(size_t)grow * N + gcol]);
          ((bf16*)Cout)[(size_t)grow * N + gcol] = __float2bfloat16(v);
        } else if constexpr (EPI == 5) {
          const int b = gcol >> 11, s = gcol & (Sc - 1);
          ((bf16*)Cout)[((size_t)(b * Hc + grow)) * Sc + s] = __float2bfloat16(v);
        } else {
          ((float*)Cout)[(size_t)grow * N + gcol] = v;
        }
      }
}

// ---------------- qk GEMM: BK=64, 2-slot counted-vmcnt, fused RoPE --------
// 256x256 tile, 512 thr (2Mx4N waves, 128x64/wave). Per tile: stage(t+1)
// [8 loads] -> vmcnt(8) [t's loads landed, t+1's in flight] -> barrier ->
// 64 MFMA/wave -> barrier. Half the barrier-pairs of BK=32; loads never
// drained in the main loop. LDS 128KB (qk was already 1 block/CU).
__global__ __launch_bounds__(512, 2) void gemm_q8(
    const bf16* __restrict__ A, const bf16* __restrict__ Bw,
    const int* __restrict__ pos, const float* __restrict__ ct,
    const float* __restrict__ st, bf16* __restrict__ qout,
    bf16* __restrict__ kout) {
  constexpr int K = Hc;                 // 2048
  __shared__ __align__(16) bf16 lds[2][32768];   // [A 16384 | B 16384] per slot
  const int tid = threadIdx.x;
  const int w = tid >> 6, l = tid & 63;
  const int lrow = l & 15, lg = l >> 4;
  const int wm = (w >> 2) * 128, wn = (w & 3) * 64;
  // rect XCD swizzle (grid 16x16)
  const int gx = gridDim.x;
  const int lin = blockIdx.y * gx + blockIdx.x;
  const int cx = gx >> 2, cy = gridDim.y >> 1;
  const int c = lin & 7, idx = lin >> 3;
  const int bn = (c & 3) * cx + idx % cx;
  const int bm = (c >> 2) * cy + idx / cx;

  auto stage = [&](int kt, int slot) {
    const int kcol = kt * 64;
    const bf16* Ab = A + (size_t)bm * 256 * K + kcol;
    const bf16* Bb = Bw + (size_t)bn * 256 * K + kcol;
    bf16* dA = lds[slot];
    bf16* dB = lds[slot] + 16384;
#pragma unroll
    for (int j = 0; j < 4; ++j) {
      const int ci = tid + j * 512;
      const int r = ci >> 3, g = (ci & 7) ^ (r & 7);
      gload16(Ab + (size_t)r * K + g * 8, dA + ci * 8);
    }
#pragma unroll
    for (int j = 0; j < 4; ++j) {
      const int ci = tid + j * 512;
      const int r = ci >> 3, g = (ci & 7) ^ (r & 7);
      gload16(Bb + (size_t)r * K + g * 8, dB + ci * 8);
    }
  };
  auto frag = [&](const bf16* base, int r, int kb) -> s16x8 {
    const int cp = (kb << 2) + lg;      // 16B chunk within the 64-elem row
    return *(const s16x8*)(base + (r * 8 + (cp ^ (r & 7))) * 8);
  };

  f32x4 acc[8][4] = {};
  stage(0, 0);
  for (int t = 0; t < K / 64; ++t) {
    if (t + 1 < K / 64) { stage(t + 1, (t + 1) & 1); vm_wait<8>(); }
    else { vm_wait<0>(); }
    block_bar();                        // tile t landed for all waves
    const bf16* Asl = lds[t & 1];
    const bf16* Bsl = Asl + 16384;
#pragma unroll
    for (int kb = 0; kb < 2; ++kb) {
      s16x8 bfr[4];
#pragma unroll
      for (int n = 0; n < 4; ++n) bfr[n] = frag(Bsl, wn + n * 16 + lrow, kb);
      __builtin_amdgcn_s_setprio(1);
#pragma unroll
      for (int m = 0; m < 8; ++m) {
        const s16x8 af = frag(Asl, wm + m * 16 + lrow, kb);
#pragma unroll
        for (int n = 0; n < 4; ++n) acc[m][n] = mfma16(af, bfr[n], acc[m][n]);
      }
      __builtin_amdgcn_s_setprio(0);
    }
    block_bar();                        // slot reads done before re-stage
  }
  // fused RoPE epilogue: wave's 64-col window = one (head, q|k) half.
  const int gcol0 = bn * 256 + wn;      // wave-uniform
  const int h = gcol0 >> 7, half = (gcol0 >> 6) & 1;
  bf16* outp = half ? kout : qout;
  const float qsc = half ? 1.0f : 0.125f * 1.44269504088896f;
#pragma unroll
  for (int m = 0; m < 8; ++m)
#pragma unroll
    for (int r = 0; r < 4; ++r) {
      const int grow = bm * 256 + wm + m * 16 + lg * 4 + r;
      const int p = pos[grow];
      const int bb = grow >> 11, s = grow & (Sc - 1);
      bf16* rowp = outp + ((size_t)(bb * NHc + h) * Sc + s) * 64;
#pragma unroll
      for (int n = 0; n < 2; ++n) {
        const int dd = n * 16 + lrow;
        const float c0 = ct[p * 64 + dd],      s0 = st[p * 64 + dd];
        const float c1 = ct[p * 64 + 32 + dd], s1 = st[p * 64 + 32 + dd];
        const float v0 = acc[m][n][r], v1 = acc[m][n + 2][r];
        rowp[dd]      = __float2bfloat16((v0 * c0 - v1 * s0) * qsc);
        rowp[dd + 32] = __float2bfloat16((v1 * c1 + v0 * s1) * qsc);
      }
    }
}

// ---------------- causal flash attention (block-staged K/V, KVBLK=64) -----
// Round-12 proven version: 256 threads / 4 waves, 2-slot double buffer,
// __syncthreads protocol, 53KB LDS -> 3 blocks/CU, VGPR 128.
__global__ __launch_bounds__(256) void k_attn(const bf16* __restrict__ Q,
                                              const bf16* __restrict__ Kg,
                                              const bf16* __restrict__ Vt,
                                              bf16* __restrict__ ctx) {
  __shared__ __align__(16) bf16 Ks[2][64 * 64];
  __shared__ __align__(16) bf16 Vs[2][64 * 64];
  __shared__ __align__(16) uint32_t Pl[4][2][2][16][20];
  const int tid = threadIdx.x;
  const int w = tid >> 6, l = tid & 63;
  const int lrow = l & 15, lg = l >> 4, lk = lg * 8;
  const int bh = blockIdx.x;
  const int tile = blockIdx.y;
  const bf16* Qp = Q  + (size_t)bh * Sc * HDc;
  const bf16* Kp = Kg + (size_t)bh * Sc * HDc;
  const bf16* Vp = Vt + (size_t)bh * HDc * Sc;
  const int b = bh >> 5, h = bh & 31;
  const s16x8 ones8 = {16256, 16256, 16256, 16256, 16256, 16256, 16256, 16256};

  const int srow0 = tid >> 3, schunk = tid & 7;

  for (int pass = 0; pass < 2; ++pass) {
    const int base = (pass == 0) ? tile * 128 : (Sc - 128 - tile * 128);
    const int q0 = base + w * 32;
    const int NT = base / 64 + 2;

    s16x8 qa[2][2];
#pragma unroll
    for (int m = 0; m < 2; ++m)
#pragma unroll
      for (int hf = 0; hf < 2; ++hf)
        qa[m][hf] = *(const s16x8*)&Qp[(size_t)(q0 + m * 16 + lrow) * 64 + hf * 32 + lk];

    f32x4 o[2][4] = {};
    f32x4 lsf[2] = {};
    float mx[2] = {-1e30f, -1e30f};

    {
      gload16(Kp + (size_t)srow0 * 64 + ((schunk ^ (srow0 & 7)) << 3), &Ks[0][tid * 8]);
      gload16(Kp + (size_t)(32 + srow0) * 64 + ((schunk ^ ((32 + srow0) & 7)) << 3),
              &Ks[0][2048 + tid * 8]);
      gload16(Vp + (size_t)srow0 * Sc + ((schunk ^ (srow0 & 7)) << 3), &Vs[0][tid * 8]);
      gload16(Vp + (size_t)(32 + srow0) * Sc + ((schunk ^ ((32 + srow0) & 7)) << 3),
              &Vs[0][2048 + tid * 8]);
    }
    __syncthreads();

    for (int t = 0; t < NT; ++t) {
      const int cur = t & 1;
      const int kv0 = t * 64;
      if (t + 1 < NT) {
        const int nkv = kv0 + 64;
        const int nb = cur ^ 1;
        gload16(Kp + (size_t)(nkv + srow0) * 64 + ((schunk ^ (srow0 & 7)) << 3),
                &Ks[nb][tid * 8]);
        gload16(Kp + (size_t)(nkv + 32 + srow0) * 64 + ((schunk ^ ((32 + srow0) & 7)) << 3),
                &Ks[nb][2048 + tid * 8]);
        gload16(Vp + (size_t)srow0 * Sc + nkv + ((schunk ^ (srow0 & 7)) << 3),
                &Vs[nb][tid * 8]);
        gload16(Vp + (size_t)(32 + srow0) * Sc + nkv + ((schunk ^ ((32 + srow0) & 7)) << 3),
                &Vs[nb][2048 + tid * 8]);
      }
      if (kv0 <= q0) {
        s16x8 kc[8], vc[4][2];
#pragma unroll
        for (int c = 0; c < 4; ++c)
#pragma unroll
          for (int hf = 0; hf < 2; ++hf) {
            const int row = c * 16 + lrow;
            kc[c * 2 + hf] =
                *(const s16x8*)&Ks[cur][row * 64 + (((hf << 2) + lg) ^ (row & 7)) * 8];
          }
#pragma unroll
        for (int db = 0; db < 4; ++db)
#pragma unroll
          for (int kh = 0; kh < 2; ++kh) {
            const int row = db * 16 + lrow;
            vc[db][kh] =
                *(const s16x8*)&Vs[cur][row * 64 + (((kh << 2) + lg) ^ (row & 7)) * 8];
          }
        const bool lastit = (kv0 + 64 > q0);

#pragma unroll
        for (int m = 0; m < 2; ++m) {
          f32x4 s[4];
          __builtin_amdgcn_s_setprio(1);
#pragma unroll
          for (int c = 0; c < 4; ++c) {
            f32x4 z = {};
            z = mfma16(kc[c * 2], qa[m][0], z);
            z = mfma16(kc[c * 2 + 1], qa[m][1], z);
            s[c] = z;
          }
          __builtin_amdgcn_s_setprio(0);

          if (lastit) {
            const int qq = q0 + m * 16 + lrow;
#pragma unroll
            for (int c = 0; c < 4; ++c)
#pragma unroll
              for (int r = 0; r < 4; ++r)
                if (kv0 + c * 16 + lg * 4 + r > qq) s[c][r] = -1e30f;
          }
          float t16 = fmaxf(
              fmaxf(fmaxf(fmaxf(s[0][0], s[0][1]), fmaxf(s[0][2], s[0][3])),
                    fmaxf(fmaxf(s[1][0], s[1][1]), fmaxf(s[1][2], s[1][3]))),
              fmaxf(fmaxf(fmaxf(s[2][0], s[2][1]), fmaxf(s[2][2], s[2][3])),
                    fmaxf(fmaxf(s[3][0], s[3][1]), fmaxf(s[3][2], s[3][3]))));
          if (!__all(t16 <= mx[m] + 8.0f)) {
            t16 = fmaxf(t16, __shfl_xor(t16, 16, 64));
            t16 = fmaxf(t16, __shfl_xor(t16, 32, 64));
            const float mnew = fmaxf(mx[m], t16);
            const float sold = __builtin_amdgcn_exp2f(mx[m] - mnew);
            mx[m] = mnew;
            lsf[m] *= sold;
#pragma unroll
            for (int db = 0; db < 4; ++db) o[m][db] *= sold;
          }
          float p[4][4];
#pragma unroll
          for (int c = 0; c < 4; ++c)
#pragma unroll
            for (int r = 0; r < 4; ++r)
              p[c][r] = __builtin_amdgcn_exp2f(s[c][r] - mx[m]);
#pragma unroll
          for (int kh = 0; kh < 2; ++kh) {
            *(uint64_t*)&Pl[w][m][kh][lrow][lg * 2] =
                pkbf4(p[kh * 2][0], p[kh * 2][1], p[kh * 2][2], p[kh * 2][3]);
            *(uint64_t*)&Pl[w][m][kh][lrow][8 + lg * 2] =
                pkbf4(p[kh * 2 + 1][0], p[kh * 2 + 1][1],
                      p[kh * 2 + 1][2], p[kh * 2 + 1][3]);
          }
          const s16x8 pb0 = *(const s16x8*)&Pl[w][m][0][lrow][lg * 4];
          const s16x8 pb1 = *(const s16x8*)&Pl[w][m][1][lrow][lg * 4];
          __builtin_amdgcn_s_setprio(1);
#pragma unroll
          for (int db = 0; db < 4; ++db) o[m][db] = mfma16(vc[db][0], pb0, o[m][db]);
          lsf[m] = mfma16(ones8, pb0, lsf[m]);
#pragma unroll
          for (int db = 0; db < 4; ++db) o[m][db] = mfma16(vc[db][1], pb1, o[m][db]);
          lsf[m] = mfma16(ones8, pb1, lsf[m]);
          __builtin_amdgcn_s_setprio(0);
        }
      }
      __syncthreads();
    }
#pragma unroll
    for (int m = 0; m < 2; ++m) {
      const float inv = 1.0f / lsf[m][0];
      const int qrow = q0 + m * 16 + lrow;
      const size_t rowoff = ((size_t)(b * Sc + qrow)) * Hc + h * 64;
#pragma unroll
      for (int db = 0; db < 4; ++db) {
        uint64_t pk = (uint64_t)bfbits(o[m][db][0] * inv) |
                      ((uint64_t)bfbits(o[m][db][1] * inv) << 16) |
                      ((uint64_t)bfbits(o[m][db][2] * inv) << 32) |
                      ((uint64_t)bfbits(o[m][db][3] * inv) << 48);
        *(uint64_t*)&ctx[rowoff + db * 16 + lg * 4] = pk;
      }
    }
    __syncthreads();
  }
}

// ---------------- host ----------------
extern "C" void kernel_launch(void* const* d_in, const int* in_sizes, int n_in,
                              void* d_out, int out_size, void* d_ws, size_t ws_size,
                              hipStream_t stream) {
  (void)in_sizes; (void)n_in; (void)out_size; (void)ws_size;
  const float* hs  = (const float*)d_in[0];
  const int*   pos = (const int*)d_in[1];
  const float* lf1 = (const float*)d_in[2];
  const float* lf2 = (const float*)d_in[3];
  const float* Wqk = (const float*)d_in[4];
  const float* Wv  = (const float*)d_in[5];
  const float* Wo  = (const float*)d_in[6];
  const float* c1w = (const float*)d_in[7];
  const float* c1b = (const float*)d_in[8];
  const float* c2w = (const float*)d_in[9];
  const float* c2b = (const float*)d_in[10];
  const float* lnw = (const float*)d_in[11];
  float* out = (float*)d_out;
  char*  ws  = (char*)d_ws;

  bf16* wvB   = (bf16*)(ws + OFF_WV);
  bf16* wqkB  = (bf16*)(ws + OFF_WQK);
  bf16* woB   = (bf16*)(ws + OFF_WO);
  bf16* w1B   = (bf16*)(ws + OFF_W1);
  bf16* w2B   = (bf16*)(ws + OFF_W2);
  bf16* hsB   = (bf16*)(ws + OFF_HS);
  bf16* xprB  = (bf16*)(ws + OFF_XPR);
  bf16* o1B   = (bf16*)(ws + OFF_O1);
  bf16* o1pB  = (bf16*)(ws + OFF_O1P);
  bf16* o2B   = (bf16*)(ws + OFF_O2);
  bf16* lfB   = (bf16*)(ws + OFF_LF);
  bf16* vtB   = (bf16*)(ws + OFF_VT);
  float* cosT = (float*)(ws + OFF_COS);
  float* sinT = (float*)(ws + OFF_SIN);
  bf16* qB    = (bf16*)(ws + OFF_Q);
  bf16* kB    = (bf16*)(ws + OFF_K);
  bf16* ctxB  = (bf16*)(ws + OFF_CTX);

  // YaRN inv_freq on host (fp64), matching the reference exactly
  InvF f;
  {
    const double base = 10000.0, scale = 2.0;
    const int hd = HDc;
    auto corr = [&](double nr) {
      return hd * log(8192.0 / (nr * 2.0 * M_PI)) / (2.0 * log(base));
    };
    double low = floor(corr(32.0)); if (low < 0) low = 0;
    double high = ceil(corr(1.0));  if (high > hd - 1) high = hd - 1;
    double hi = (low == high) ? high + 0.001 : high;
    for (int i = 0; i < 32; ++i) {
      double inv = 1.0 / pow(base, (2.0 * i) / hd);
      double ramp = ((double)i - low) / (hi - low);
      ramp = ramp < 0.0 ? 0.0 : (ramp > 1.0 ? 1.0 : ramp);
      double mask = 1.0 - ramp;
      f.v[i] = inv / ((1.0 - mask) * scale + mask);
    }
    f.mscale = 0.1 * log(scale) + 1.0;
  }

  // fused preprocessing (weights + tables + prefill) and hs conversion
  k_prep<<<100360, 256, 0, stream>>>(Wv, Wqk, Wo, c1w, c2w, lf2, f,
                                     wvB, wqkB, woB, w1B, w2B, o1pB, cosT, sinT);
  k_cvt_hs4<<<(Mc * Hc / 4 + 255) / 256, 256, 0, stream>>>(hs, lf1, hsB, xprB);

  // conv1: o1 = [xprev|x] @ w1cat^T + b1  (gemm8 128x128, grid 8x32)
  gemm8<1, 128, 128><<<dim3((Hc / 2) / 128, Mc / 128), 512, 0, stream>>>(
      xprB, hsB, Hc, w1B, 2 * Hc, Hc / 2, o1B, c1b, o1pB);
  // v^T: C'[hd][(b,s)] = Wv @ hs^T
  gemm8<5, 256, 128><<<dim3(Mc / 128, Hc / 256), 512, 0, stream>>>(
      wvB, wvB, Hc, hsB, Hc, Mc, vtB, nullptr, nullptr);
  // conv2: o2res = [o1prev|o1] @ w2cat^T + b2 + hs(bf16)  -> bf16
  gemm8<2, 256, 128><<<dim3(Hc / 128, Mc / 256), 512, 0, stream>>>(
      o1pB, o1B, Hc / 2, w2B, Hc, Hc, o2B, c2b, hsB);
  // lf = rmsnorm(o2res) * ln_w   (bf16 in/out, vectorized)
  k_rmsnorm<<<Mc, 256, 0, stream>>>(o2B, lnw, lfB);
  // qk = lf @ Wqk^T with fused RoPE (BK=64 counted-vmcnt kernel)
  gemm_q8<<<dim3((2 * Hc) / 256, Mc / 256), 512, 0, stream>>>(
      lfB, wqkB, pos, cosT, sinT, qB, kB);
  // causal flash attention -> ctx (b,s,h*64+d)
  k_attn<<<dim3(64, 8), 256, 0, stream>>>(qB, kB, vtB, ctxB);
  // out = ctx @ Wo^T  (fp32)
  gemm8<4, 256, 128><<<dim3(Hc / 128, Mc / 256), 512, 0, stream>>>(
      ctxB, ctxB, Hc, woB, Hc, Hc, out, nullptr, nullptr);
}

// Round 16
// 404.386 us; speedup vs baseline: 1.3978x; 1.0029x over previous
//
#include <hip/hip_runtime.h>
#include <hip/hip_bf16.h>
#include <math.h>
#include <stdint.h>

typedef __hip_bfloat16 bf16;
using f32x4 = __attribute__((ext_vector_type(4))) float;
using s16x8 = __attribute__((ext_vector_type(8))) short;

constexpr int Bc = 2, Sc = 2048, Hc = 2048, NHc = 32, HDc = 64;
constexpr int Mc = Bc * Sc;      // 4096 rows
constexpr int MAXPOS = 8192;

// ---------------- workspace layout (bytes) ----------------
constexpr size_t OFF_WV  = 0;
constexpr size_t OFF_WQK = OFF_WV  + (size_t)Hc * Hc * 2;
constexpr size_t OFF_WO  = OFF_WQK + (size_t)2 * Hc * Hc * 2;
constexpr size_t OFF_W1  = OFF_WO  + (size_t)Hc * Hc * 2;
constexpr size_t OFF_W2  = OFF_W1  + (size_t)(Hc/2) * (2*Hc) * 2;
constexpr size_t OFF_HS  = OFF_W2  + (size_t)Hc * Hc * 2;
constexpr size_t OFF_XPR = OFF_HS  + (size_t)Mc * Hc * 2;
constexpr size_t OFF_O1  = OFF_XPR + (size_t)Mc * Hc * 2;
constexpr size_t OFF_O1P = OFF_O1  + (size_t)Mc * (Hc/2) * 2;
constexpr size_t OFF_O2  = OFF_O1P + (size_t)Mc * (Hc/2) * 2;   // o2res bf16 now
constexpr size_t OFF_LF  = OFF_O2  + (size_t)Mc * Hc * 4;
constexpr size_t OFF_VT  = OFF_LF  + (size_t)Mc * Hc * 2;
constexpr size_t OFF_COS = OFF_VT  + (size_t)Mc * Hc * 2;
constexpr size_t OFF_SIN = OFF_COS + (size_t)MAXPOS * HDc * 4;
constexpr size_t OFF_Q   = OFF_XPR;  // q over xprev
constexpr size_t OFF_K   = OFF_HS;   // k over hs
constexpr size_t OFF_CTX = OFF_O1;   // ctx over o1+o1prev

// ---------------- helpers ----------------
__device__ __forceinline__ f32x4 mfma16(s16x8 a, s16x8 b, f32x4 c) {
  return __builtin_amdgcn_mfma_f32_16x16x32_bf16(a, b, c, 0, 0, 0);
}
__device__ __forceinline__ void gload16(const bf16* g, bf16* l) {
  __builtin_amdgcn_global_load_lds(
      (__attribute__((address_space(1))) void*)g,
      (__attribute__((address_space(3))) void*)l, 16, 0, 0);
}
__device__ __forceinline__ uint16_t bfbits(float x) {
  union { bf16 h; uint16_t u; } v; v.h = __float2bfloat16(x); return v.u;
}
__device__ __forceinline__ float bff(uint16_t u) {
  union { bf16 h; uint16_t u; } v; v.u = u; return __bfloat162float(v.h);
}
__device__ __forceinline__ uint32_t pkbf(float a, float b) {
  return (uint32_t)bfbits(a) | ((uint32_t)bfbits(b) << 16);
}
__device__ __forceinline__ uint64_t pkbf4(float a, float b, float c, float d) {
  return (uint64_t)pkbf(a, b) | ((uint64_t)pkbf(c, d) << 32);
}
__device__ __forceinline__ void block_bar() {
  asm volatile("" ::: "memory");
  __builtin_amdgcn_s_barrier();
  asm volatile("" ::: "memory");
}
template <int N> __device__ __forceinline__ void vm_wait() {
  if constexpr (N == 0)      asm volatile("s_waitcnt vmcnt(0)" ::: "memory");
  else if constexpr (N == 2) asm volatile("s_waitcnt vmcnt(2)" ::: "memory");
  else if constexpr (N == 3) asm volatile("s_waitcnt vmcnt(3)" ::: "memory");
  else if constexpr (N == 4) asm volatile("s_waitcnt vmcnt(4)" ::: "memory");
  else if constexpr (N == 6) asm volatile("s_waitcnt vmcnt(6)" ::: "memory");
  else if constexpr (N == 8) asm volatile("s_waitcnt vmcnt(8)" ::: "memory");
}

struct InvF { double v[32]; double mscale; };

// ---------------- fused preprocessing (1 launch replaces 7) ---------------
// block ranges: [0,16384) wv | [16384,49152) wqk | [49152,65536) wo |
// [65536,81920) repack1 | [81920,98304) repack2 | [98304,100352) costab |
// [100352,100360) prefill o1p
__global__ void k_prep(const float* __restrict__ Wv, const float* __restrict__ Wqk,
                       const float* __restrict__ Wo, const float* __restrict__ c1w,
                       const float* __restrict__ c2w, const float* __restrict__ lf2,
                       InvF f, bf16* __restrict__ wv, bf16* __restrict__ wqk,
                       bf16* __restrict__ wo, bf16* __restrict__ w1,
                       bf16* __restrict__ w2, bf16* __restrict__ o1p,
                       float* __restrict__ ct, float* __restrict__ st) {
  const int blk = blockIdx.x, tid = threadIdx.x;
  if (blk < 16384) {
    const int i = blk * 256 + tid;
    wv[i] = __float2bfloat16(Wv[i]);
  } else if (blk < 49152) {
    const int i = (blk - 16384) * 256 + tid;
    wqk[i] = __float2bfloat16(Wqk[i]);
  } else if (blk < 65536) {
    const int i = (blk - 49152) * 256 + tid;
    wo[i] = __float2bfloat16(Wo[i]);
  } else if (blk < 81920) {
    const int i = (blk - 65536) * 256 + tid;   // 1024*4096
    const int oc = i >> 12, k = i & 4095;
    const int ic = k & (Hc - 1), t = k >> 11;
    w1[i] = __float2bfloat16(c1w[((size_t)oc * Hc + ic) * 2 + t]);
  } else if (blk < 98304) {
    const int i = (blk - 81920) * 256 + tid;   // 2048*2048
    const int c = i >> 11, k = i & (Hc - 1);
    const int oc = k & (Hc / 2 - 1), t = k >> 10;
    w2[i] = __float2bfloat16(c2w[((size_t)c * (Hc / 2) + oc) * 2 + t]);
  } else if (blk < 100352) {
    const int i = (blk - 98304) * 256 + tid;   // MAXPOS*64
    const int p = i >> 6, d = i & 63;
    const double ang = (double)p * f.v[d & 31];
    ct[i] = (float)(cos(ang) * f.mscale);
    st[i] = (float)(sin(ang) * f.mscale);
  } else {
    const int i = (blk - 100352) * 256 + tid;  // B * H/2
    if (i < Bc * (Hc / 2)) {
      const int b = i >> 10, n = i & (Hc / 2 - 1);
      o1p[(size_t)b * Sc * (Hc / 2) + n] = __float2bfloat16(lf2[i]);
    }
  }
}

// hs fp32 -> hs bf16 and xprev (row-shifted, lf1 at s==0), 4 elems/thread
__global__ void k_cvt_hs4(const float* __restrict__ hs, const float* __restrict__ lf1,
                          bf16* __restrict__ hsb, bf16* __restrict__ xprev) {
  const int i = (blockIdx.x * 256 + threadIdx.x) * 4;   // over M*H
  if (i >= Mc * Hc) return;
  const float4 v = *(const float4*)(hs + i);
  const uint64_t pk = pkbf4(v.x, v.y, v.z, v.w);
  *(uint64_t*)(hsb + i) = pk;
  const int row = i >> 11, s = row & (Sc - 1), bb = row >> 11, col = i & (Hc - 1);
  if (s + 1 < Sc) *(uint64_t*)(xprev + i + Hc) = pk;
  if (s == 0) {
    const float4 lv = *(const float4*)(lf1 + bb * Hc + col);
    *(uint64_t*)(xprev + i) = pkbf4(lv.x, lv.y, lv.z, lv.w);
  }
}

// ---------------- RMSNorm (block per row, bf16 input, vectorized) ---------
__global__ __launch_bounds__(256) void k_rmsnorm(const bf16* __restrict__ x,
                                                 const float* __restrict__ w,
                                                 bf16* __restrict__ out) {
  __shared__ float red[4];
  const int row = blockIdx.x, tid = threadIdx.x;
  const s16x8 v = *(const s16x8*)(x + (size_t)row * Hc + tid * 8);
  float fv[8];
  float ss = 0.f;
#pragma unroll
  for (int j = 0; j < 8; ++j) {
    fv[j] = bff((uint16_t)v[j]);
    ss += fv[j] * fv[j];
  }
  for (int off = 32; off; off >>= 1) ss += __shfl_down(ss, off, 64);
  if ((tid & 63) == 0) red[tid >> 6] = ss;
  __syncthreads();
  const float sc = rsqrtf((red[0] + red[1] + red[2] + red[3]) / Hc + 1e-6f);
  const float4 w0 = *(const float4*)(w + tid * 8);
  const float4 w1 = *(const float4*)(w + tid * 8 + 4);
  uint64_t lo = pkbf4(fv[0] * sc * w0.x, fv[1] * sc * w0.y,
                      fv[2] * sc * w0.z, fv[3] * sc * w0.w);
  uint64_t hi = pkbf4(fv[4] * sc * w1.x, fv[5] * sc * w1.y,
                      fv[6] * sc * w1.z, fv[7] * sc * w1.w);
  uint64_t* op = (uint64_t*)(out + (size_t)row * Hc + tid * 8);
  op[0] = lo; op[1] = hi;
}

// ---------------- triple-buffered counted-vmcnt GEMM (512 thr, 8 waves) ---
// EPI: 1 conv1 (+bias, dual store via out2) | 2 +bias + bf16 resid(out2),
//      bf16 out | 4 fp32 | 5 v^T store
template <int EPI, int BM, int BN>
__global__ __launch_bounds__(512, 2) void gemm8(
    const bf16* __restrict__ A0, const bf16* __restrict__ A1, int Ksplit,
    const bf16* __restrict__ Bw, int K, int N, void* __restrict__ Cout,
    const float* __restrict__ bias, bf16* __restrict__ out2) {
  constexpr int L = (BM + BN) / 128;            // gload16 per thread per tile
  constexpr int TILE = (BM + BN) * 32;
  constexpr int MF = (BM == 256) ? 4 : 4;
  constexpr int NF = (BM == 256) ? 4 : 2;
  __shared__ __align__(16) bf16 lds[3][TILE];
  const int tid = threadIdx.x;
  const int w = tid >> 6, l = tid & 63;
  const int lrow = l & 15, lg = l >> 4;
  const int wm = (BM == 256) ? (w & 3) * 64 : (w >> 2) * 64;
  const int wn = (BM == 256) ? (w >> 2) * 64 : (w & 3) * 32;
  // rect XCD swizzle: XCD c gets a (gx/4)x(gy/2) block rectangle
  const int gx = gridDim.x;
  const int lin = blockIdx.y * gx + blockIdx.x;
  const int cx = gx >> 2, cy = gridDim.y >> 1;
  const int c = lin & 7, idx = lin >> 3;
  const int bn = (c & 3) * cx + idx % cx;
  const int bm = (c >> 2) * cy + idx / cx;

  auto ld1 = [&](const bf16* srcbase, size_t stride, bf16* ldst, int ci) {
    const int pr = ci >> 3, rem = ci & 7;
    const int r = pr * 2 + (rem >> 2), g = (rem & 3) ^ (pr & 3);
    gload16(srcbase + (size_t)r * stride + g * 8, ldst + ci * 8);
  };
  auto stage = [&](int kt, int slot) {
    const int kcol = kt * 32;
    const bf16* Au; int kc;
    if (kcol < Ksplit) { Au = A0; kc = kcol; } else { Au = A1; kc = kcol - Ksplit; }
    const bf16* As_ = Au + (size_t)bm * BM * Ksplit + kc;
    bf16* ldsA = lds[slot];
    ld1(As_, Ksplit, ldsA, tid);
    if constexpr (BM == 256) ld1(As_, Ksplit, ldsA, tid + 512);
    const bf16* Bs_ = Bw + (size_t)bn * BN * K + kcol;
    bf16* ldsB = lds[slot] + BM * 32;
    ld1(Bs_, K, ldsB, tid);
    if constexpr (BN == 256) ld1(Bs_, K, ldsB, tid + 512);
  };
  auto frag = [&](const bf16* base, int r) -> s16x8 {
    const int s = ((r >> 1) << 3) + ((r & 1) << 2) + (lg ^ ((r >> 1) & 3));
    return *(const s16x8*)(base + s * 8);
  };

  f32x4 acc[MF][NF] = {};
  const int nkt = K / 32;
  stage(0, 0);
  stage(1, 1);
  for (int t = 0; t < nkt; ++t) {
    if (t + 2 < nkt) { stage(t + 2, (t + 2) % 3); vm_wait<2 * L>(); }
    else if (t + 1 < nkt) { vm_wait<L>(); }
    else { vm_wait<0>(); }
    block_bar();
    const bf16* Asl = lds[t % 3];
    const bf16* Bsl = Asl + BM * 32;
    s16x8 af[MF], bfr[NF];
#pragma unroll
    for (int m = 0; m < MF; ++m) af[m] = frag(Asl, wm + m * 16 + lrow);
#pragma unroll
    for (int n = 0; n < NF; ++n) bfr[n] = frag(Bsl, wn + n * 16 + lrow);
    __builtin_amdgcn_s_setprio(1);
#pragma unroll
    for (int m = 0; m < MF; ++m)
#pragma unroll
      for (int n = 0; n < NF; ++n)
        acc[m][n] = mfma16(af[m], bfr[n], acc[m][n]);
    __builtin_amdgcn_s_setprio(0);
    block_bar();
  }
#pragma unroll
  for (int m = 0; m < MF; ++m)
#pragma unroll
    for (int n = 0; n < NF; ++n)
#pragma unroll
      for (int r = 0; r < 4; ++r) {
        const int grow = bm * BM + wm + m * 16 + lg * 4 + r;
        const int gcol = bn * BN + wn + n * 16 + lrow;
        float v = acc[m][n][r];
        if constexpr (EPI == 1) {
          v += bias[gcol];
          bf16 bv = __float2bfloat16(v);
          ((bf16*)Cout)[(size_t)grow * N + gcol] = bv;
          if ((grow & (Sc - 1)) != Sc - 1) out2[(size_t)(grow + 1) * N + gcol] = bv;
        } else if constexpr (EPI == 2) {
          v += bias[gcol] + __bfloat162float(out2[(size_t)grow * N + gcol]);
          ((bf16*)Cout)[(size_t)grow * N + gcol] = __float2bfloat16(v);
        } else if constexpr (EPI == 5) {
          const int b = gcol >> 11, s = gcol & (Sc - 1);
          ((bf16*)Cout)[((size_t)(b * Hc + grow)) * Sc + s] = __float2bfloat16(v);
        } else {
          ((float*)Cout)[(size_t)grow * N + gcol] = v;
        }
      }
}

// ---------------- qk GEMM: BK=64, 2-slot counted-vmcnt, fused RoPE --------
// 256x256 tile, 512 thr (2Mx4N waves, 128x64/wave). Per tile: stage(t+1)
// [8 loads] -> vmcnt(8) [t's loads landed, t+1's in flight] -> barrier ->
// 64 MFMA/wave -> barrier. Half the barrier-pairs of BK=32; loads never
// drained in the main loop. LDS 128KB (qk was already 1 block/CU).
__global__ __launch_bounds__(512, 2) void gemm_q8(
    const bf16* __restrict__ A, const bf16* __restrict__ Bw,
    const int* __restrict__ pos, const float* __restrict__ ct,
    const float* __restrict__ st, bf16* __restrict__ qout,
    bf16* __restrict__ kout) {
  constexpr int K = Hc;                 // 2048
  __shared__ __align__(16) bf16 lds[2][32768];   // [A 16384 | B 16384] per slot
  const int tid = threadIdx.x;
  const int w = tid >> 6, l = tid & 63;
  const int lrow = l & 15, lg = l >> 4;
  const int wm = (w >> 2) * 128, wn = (w & 3) * 64;
  // rect XCD swizzle (grid 16x16)
  const int gx = gridDim.x;
  const int lin = blockIdx.y * gx + blockIdx.x;
  const int cx = gx >> 2, cy = gridDim.y >> 1;
  const int c = lin & 7, idx = lin >> 3;
  const int bn = (c & 3) * cx + idx % cx;
  const int bm = (c >> 2) * cy + idx / cx;

  auto stage = [&](int kt, int slot) {
    const int kcol = kt * 64;
    const bf16* Ab = A + (size_t)bm * 256 * K + kcol;
    const bf16* Bb = Bw + (size_t)bn * 256 * K + kcol;
    bf16* dA = lds[slot];
    bf16* dB = lds[slot] + 16384;
#pragma unroll
    for (int j = 0; j < 4; ++j) {
      const int ci = tid + j * 512;
      const int r = ci >> 3, g = (ci & 7) ^ (r & 7);
      gload16(Ab + (size_t)r * K + g * 8, dA + ci * 8);
    }
#pragma unroll
    for (int j = 0; j < 4; ++j) {
      const int ci = tid + j * 512;
      const int r = ci >> 3, g = (ci & 7) ^ (r & 7);
      gload16(Bb + (size_t)r * K + g * 8, dB + ci * 8);
    }
  };
  auto frag = [&](const bf16* base, int r, int kb) -> s16x8 {
    const int cp = (kb << 2) + lg;      // 16B chunk within the 64-elem row
    return *(const s16x8*)(base + (r * 8 + (cp ^ (r & 7))) * 8);
  };

  f32x4 acc[8][4] = {};
  stage(0, 0);
  for (int t = 0; t < K / 64; ++t) {
    if (t + 1 < K / 64) { stage(t + 1, (t + 1) & 1); vm_wait<8>(); }
    else { vm_wait<0>(); }
    block_bar();                        // tile t landed for all waves
    const bf16* Asl = lds[t & 1];
    const bf16* Bsl = Asl + 16384;
#pragma unroll
    for (int kb = 0; kb < 2; ++kb) {
      s16x8 bfr[4];
#pragma unroll
      for (int n = 0; n < 4; ++n) bfr[n] = frag(Bsl, wn + n * 16 + lrow, kb);
      __builtin_amdgcn_s_setprio(1);
#pragma unroll
      for (int m = 0; m < 8; ++m) {
        const s16x8 af = frag(Asl, wm + m * 16 + lrow, kb);
#pragma unroll
        for (int n = 0; n < 4; ++n) acc[m][n] = mfma16(af, bfr[n], acc[m][n]);
      }
      __builtin_amdgcn_s_setprio(0);
    }
    block_bar();                        // slot reads done before re-stage
  }
  // fused RoPE epilogue: wave's 64-col window = one (head, q|k) half.
  const int gcol0 = bn * 256 + wn;      // wave-uniform
  const int h = gcol0 >> 7, half = (gcol0 >> 6) & 1;
  bf16* outp = half ? kout : qout;
  const float qsc = half ? 1.0f : 0.125f * 1.44269504088896f;
#pragma unroll
  for (int m = 0; m < 8; ++m)
#pragma unroll
    for (int r = 0; r < 4; ++r) {
      const int grow = bm * 256 + wm + m * 16 + lg * 4 + r;
      const int p = pos[grow];
      const int bb = grow >> 11, s = grow & (Sc - 1);
      bf16* rowp = outp + ((size_t)(bb * NHc + h) * Sc + s) * 64;
#pragma unroll
      for (int n = 0; n < 2; ++n) {
        const int dd = n * 16 + lrow;
        const float c0 = ct[p * 64 + dd],      s0 = st[p * 64 + dd];
        const float c1 = ct[p * 64 + 32 + dd], s1 = st[p * 64 + 32 + dd];
        const float v0 = acc[m][n][r], v1 = acc[m][n + 2][r];
        rowp[dd]      = __float2bfloat16((v0 * c0 - v1 * s0) * qsc);
        rowp[dd + 32] = __float2bfloat16((v1 * c1 + v0 * s1) * qsc);
      }
    }
}

// ---------------- causal flash attention (block-staged K/V, KVBLK=64) -----
// Round-12 proven version: 256 threads / 4 waves, 2-slot double buffer,
// __syncthreads protocol, 53KB LDS -> 3 blocks/CU, VGPR 128.
__global__ __launch_bounds__(256) void k_attn(const bf16* __restrict__ Q,
                                              const bf16* __restrict__ Kg,
                                              const bf16* __restrict__ Vt,
                                              bf16* __restrict__ ctx) {
  __shared__ __align__(16) bf16 Ks[2][64 * 64];
  __shared__ __align__(16) bf16 Vs[2][64 * 64];
  __shared__ __align__(16) uint32_t Pl[4][2][2][16][20];
  const int tid = threadIdx.x;
  const int w = tid >> 6, l = tid & 63;
  const int lrow = l & 15, lg = l >> 4, lk = lg * 8;
  const int bh = blockIdx.x;
  const int tile = blockIdx.y;
  const bf16* Qp = Q  + (size_t)bh * Sc * HDc;
  const bf16* Kp = Kg + (size_t)bh * Sc * HDc;
  const bf16* Vp = Vt + (size_t)bh * HDc * Sc;
  const int b = bh >> 5, h = bh & 31;
  const s16x8 ones8 = {16256, 16256, 16256, 16256, 16256, 16256, 16256, 16256};

  const int srow0 = tid >> 3, schunk = tid & 7;

  for (int pass = 0; pass < 2; ++pass) {
    const int base = (pass == 0) ? tile * 128 : (Sc - 128 - tile * 128);
    const int q0 = base + w * 32;
    const int NT = base / 64 + 2;

    s16x8 qa[2][2];
#pragma unroll
    for (int m = 0; m < 2; ++m)
#pragma unroll
      for (int hf = 0; hf < 2; ++hf)
        qa[m][hf] = *(const s16x8*)&Qp[(size_t)(q0 + m * 16 + lrow) * 64 + hf * 32 + lk];

    f32x4 o[2][4] = {};
    f32x4 lsf[2] = {};
    float mx[2] = {-1e30f, -1e30f};

    {
      gload16(Kp + (size_t)srow0 * 64 + ((schunk ^ (srow0 & 7)) << 3), &Ks[0][tid * 8]);
      gload16(Kp + (size_t)(32 + srow0) * 64 + ((schunk ^ ((32 + srow0) & 7)) << 3),
              &Ks[0][2048 + tid * 8]);
      gload16(Vp + (size_t)srow0 * Sc + ((schunk ^ (srow0 & 7)) << 3), &Vs[0][tid * 8]);
      gload16(Vp + (size_t)(32 + srow0) * Sc + ((schunk ^ ((32 + srow0) & 7)) << 3),
              &Vs[0][2048 + tid * 8]);
    }
    __syncthreads();

    for (int t = 0; t < NT; ++t) {
      const int cur = t & 1;
      const int kv0 = t * 64;
      if (t + 1 < NT) {
        const int nkv = kv0 + 64;
        const int nb = cur ^ 1;
        gload16(Kp + (size_t)(nkv + srow0) * 64 + ((schunk ^ (srow0 & 7)) << 3),
                &Ks[nb][tid * 8]);
        gload16(Kp + (size_t)(nkv + 32 + srow0) * 64 + ((schunk ^ ((32 + srow0) & 7)) << 3),
                &Ks[nb][2048 + tid * 8]);
        gload16(Vp + (size_t)srow0 * Sc + nkv + ((schunk ^ (srow0 & 7)) << 3),
                &Vs[nb][tid * 8]);
        gload16(Vp + (size_t)(32 + srow0) * Sc + nkv + ((schunk ^ ((32 + srow0) & 7)) << 3),
                &Vs[nb][2048 + tid * 8]);
      }
      if (kv0 <= q0) {
        s16x8 kc[8], vc[4][2];
#pragma unroll
        for (int c = 0; c < 4; ++c)
#pragma unroll
          for (int hf = 0; hf < 2; ++hf) {
            const int row = c * 16 + lrow;
            kc[c * 2 + hf] =
                *(const s16x8*)&Ks[cur][row * 64 + (((hf << 2) + lg) ^ (row & 7)) * 8];
          }
#pragma unroll
        for (int db = 0; db < 4; ++db)
#pragma unroll
          for (int kh = 0; kh < 2; ++kh) {
            const int row = db * 16 + lrow;
            vc[db][kh] =
                *(const s16x8*)&Vs[cur][row * 64 + (((kh << 2) + lg) ^ (row & 7)) * 8];
          }
        const bool lastit = (kv0 + 64 > q0);

#pragma unroll
        for (int m = 0; m < 2; ++m) {
          f32x4 s[4];
          __builtin_amdgcn_s_setprio(1);
#pragma unroll
          for (int c = 0; c < 4; ++c) {
            f32x4 z = {};
            z = mfma16(kc[c * 2], qa[m][0], z);
            z = mfma16(kc[c * 2 + 1], qa[m][1], z);
            s[c] = z;
          }
          __builtin_amdgcn_s_setprio(0);

          if (lastit) {
            const int qq = q0 + m * 16 + lrow;
#pragma unroll
            for (int c = 0; c < 4; ++c)
#pragma unroll
              for (int r = 0; r < 4; ++r)
                if (kv0 + c * 16 + lg * 4 + r > qq) s[c][r] = -1e30f;
          }
          float t16 = fmaxf(
              fmaxf(fmaxf(fmaxf(s[0][0], s[0][1]), fmaxf(s[0][2], s[0][3])),
                    fmaxf(fmaxf(s[1][0], s[1][1]), fmaxf(s[1][2], s[1][3]))),
              fmaxf(fmaxf(fmaxf(s[2][0], s[2][1]), fmaxf(s[2][2], s[2][3])),
                    fmaxf(fmaxf(s[3][0], s[3][1]), fmaxf(s[3][2], s[3][3]))));
          if (!__all(t16 <= mx[m] + 8.0f)) {
            t16 = fmaxf(t16, __shfl_xor(t16, 16, 64));
            t16 = fmaxf(t16, __shfl_xor(t16, 32, 64));
            const float mnew = fmaxf(mx[m], t16);
            const float sold = __builtin_amdgcn_exp2f(mx[m] - mnew);
            mx[m] = mnew;
            lsf[m] *= sold;
#pragma unroll
            for (int db = 0; db < 4; ++db) o[m][db] *= sold;
          }
          float p[4][4];
#pragma unroll
          for (int c = 0; c < 4; ++c)
#pragma unroll
            for (int r = 0; r < 4; ++r)
              p[c][r] = __builtin_amdgcn_exp2f(s[c][r] - mx[m]);
#pragma unroll
          for (int kh = 0; kh < 2; ++kh) {
            *(uint64_t*)&Pl[w][m][kh][lrow][lg * 2] =
                pkbf4(p[kh * 2][0], p[kh * 2][1], p[kh * 2][2], p[kh * 2][3]);
            *(uint64_t*)&Pl[w][m][kh][lrow][8 + lg * 2] =
                pkbf4(p[kh * 2 + 1][0], p[kh * 2 + 1][1],
                      p[kh * 2 + 1][2], p[kh * 2 + 1][3]);
          }
          const s16x8 pb0 = *(const s16x8*)&Pl[w][m][0][lrow][lg * 4];
          const s16x8 pb1 = *(const s16x8*)&Pl[w][m][1][lrow][lg * 4];
          __builtin_amdgcn_s_setprio(1);
#pragma unroll
          for (int db = 0; db < 4; ++db) o[m][db] = mfma16(vc[db][0], pb0, o[m][db]);
          lsf[m] = mfma16(ones8, pb0, lsf[m]);
#pragma unroll
          for (int db = 0; db < 4; ++db) o[m][db] = mfma16(vc[db][1], pb1, o[m][db]);
          lsf[m] = mfma16(ones8, pb1, lsf[m]);
          __builtin_amdgcn_s_setprio(0);
        }
      }
      __syncthreads();
    }
#pragma unroll
    for (int m = 0; m < 2; ++m) {
      const float inv = 1.0f / lsf[m][0];
      const int qrow = q0 + m * 16 + lrow;
      const size_t rowoff = ((size_t)(b * Sc + qrow)) * Hc + h * 64;
#pragma unroll
      for (int db = 0; db < 4; ++db) {
        uint64_t pk = (uint64_t)bfbits(o[m][db][0] * inv) |
                      ((uint64_t)bfbits(o[m][db][1] * inv) << 16) |
                      ((uint64_t)bfbits(o[m][db][2] * inv) << 32) |
                      ((uint64_t)bfbits(o[m][db][3] * inv) << 48);
        *(uint64_t*)&ctx[rowoff + db * 16 + lg * 4] = pk;
      }
    }
    __syncthreads();
  }
}

// ---------------- host ----------------
extern "C" void kernel_launch(void* const* d_in, const int* in_sizes, int n_in,
                              void* d_out, int out_size, void* d_ws, size_t ws_size,
                              hipStream_t stream) {
  (void)in_sizes; (void)n_in; (void)out_size; (void)ws_size;
  const float* hs  = (const float*)d_in[0];
  const int*   pos = (const int*)d_in[1];
  const float* lf1 = (const float*)d_in[2];
  const float* lf2 = (const float*)d_in[3];
  const float* Wqk = (const float*)d_in[4];
  const float* Wv  = (const float*)d_in[5];
  const float* Wo  = (const float*)d_in[6];
  const float* c1w = (const float*)d_in[7];
  const float* c1b = (const float*)d_in[8];
  const float* c2w = (const float*)d_in[9];
  const float* c2b = (const float*)d_in[10];
  const float* lnw = (const float*)d_in[11];
  float* out = (float*)d_out;
  char*  ws  = (char*)d_ws;

  bf16* wvB   = (bf16*)(ws + OFF_WV);
  bf16* wqkB  = (bf16*)(ws + OFF_WQK);
  bf16* woB   = (bf16*)(ws + OFF_WO);
  bf16* w1B   = (bf16*)(ws + OFF_W1);
  bf16* w2B   = (bf16*)(ws + OFF_W2);
  bf16* hsB   = (bf16*)(ws + OFF_HS);
  bf16* xprB  = (bf16*)(ws + OFF_XPR);
  bf16* o1B   = (bf16*)(ws + OFF_O1);
  bf16* o1pB  = (bf16*)(ws + OFF_O1P);
  bf16* o2B   = (bf16*)(ws + OFF_O2);
  bf16* lfB   = (bf16*)(ws + OFF_LF);
  bf16* vtB   = (bf16*)(ws + OFF_VT);
  float* cosT = (float*)(ws + OFF_COS);
  float* sinT = (float*)(ws + OFF_SIN);
  bf16* qB    = (bf16*)(ws + OFF_Q);
  bf16* kB    = (bf16*)(ws + OFF_K);
  bf16* ctxB  = (bf16*)(ws + OFF_CTX);

  // YaRN inv_freq on host (fp64), matching the reference exactly
  InvF f;
  {
    const double base = 10000.0, scale = 2.0;
    const int hd = HDc;
    auto corr = [&](double nr) {
      return hd * log(8192.0 / (nr * 2.0 * M_PI)) / (2.0 * log(base));
    };
    double low = floor(corr(32.0)); if (low < 0) low = 0;
    double high = ceil(corr(1.0));  if (high > hd - 1) high = hd - 1;
    double hi = (low == high) ? high + 0.001 : high;
    for (int i = 0; i < 32; ++i) {
      double inv = 1.0 / pow(base, (2.0 * i) / hd);
      double ramp = ((double)i - low) / (hi - low);
      ramp = ramp < 0.0 ? 0.0 : (ramp > 1.0 ? 1.0 : ramp);
      double mask = 1.0 - ramp;
      f.v[i] = inv / ((1.0 - mask) * scale + mask);
    }
    f.mscale = 0.1 * log(scale) + 1.0;
  }

  // fused preprocessing (weights + tables + prefill) and hs conversion
  k_prep<<<100360, 256, 0, stream>>>(Wv, Wqk, Wo, c1w, c2w, lf2, f,
                                     wvB, wqkB, woB, w1B, w2B, o1pB, cosT, sinT);
  k_cvt_hs4<<<(Mc * Hc / 4 + 255) / 256, 256, 0, stream>>>(hs, lf1, hsB, xprB);

  // conv1: o1 = [xprev|x] @ w1cat^T + b1  (gemm8 128x128, grid 8x32)
  gemm8<1, 128, 128><<<dim3((Hc / 2) / 128, Mc / 128), 512, 0, stream>>>(
      xprB, hsB, Hc, w1B, 2 * Hc, Hc / 2, o1B, c1b, o1pB);
  // v^T: C'[hd][(b,s)] = Wv @ hs^T
  gemm8<5, 256, 128><<<dim3(Mc / 128, Hc / 256), 512, 0, stream>>>(
      wvB, wvB, Hc, hsB, Hc, Mc, vtB, nullptr, nullptr);
  // conv2: o2res = [o1prev|o1] @ w2cat^T + b2 + hs(bf16)  -> bf16
  gemm8<2, 256, 128><<<dim3(Hc / 128, Mc / 256), 512, 0, stream>>>(
      o1pB, o1B, Hc / 2, w2B, Hc, Hc, o2B, c2b, hsB);
  // lf = rmsnorm(o2res) * ln_w   (bf16 in/out, vectorized)
  k_rmsnorm<<<Mc, 256, 0, stream>>>(o2B, lnw, lfB);
  // qk = lf @ Wqk^T with fused RoPE (BK=64 counted-vmcnt kernel)
  gemm_q8<<<dim3((2 * Hc) / 256, Mc / 256), 512, 0, stream>>>(
      lfB, wqkB, pos, cosT, sinT, qB, kB);
  // causal flash attention -> ctx (b,s,h*64+d)
  k_attn<<<dim3(64, 8), 256, 0, stream>>>(qB, kB, vtB, ctxB);
  // out = ctx @ Wo^T  (fp32)
  gemm8<4, 256, 128><<<dim3(Hc / 128, Mc / 256), 512, 0, stream>>>(
      ctxB, ctxB, Hc, woB, Hc, Hc, out, nullptr, nullptr);
}